// Round 3
// baseline (2936.735 us; speedup 1.0000x reference)
//
#include <hip/hip_runtime.h>
#include <cstdint>

#define L_LAYERS 6

typedef __attribute__((ext_vector_type(8))) short bf16x8;
typedef __attribute__((ext_vector_type(4))) float f32x4;

__device__ __forceinline__ float gelu1(float v) {
    return 0.5f * v * (1.0f + erff(v * 0.7071067811865475f));
}

// pack two fp32 into two bf16 (round-nearest-even), low|high
__device__ __forceinline__ unsigned int f2bf2(float a, float b) {
    union { float f; unsigned u; } x, y;
    x.f = a; y.f = b;
    unsigned lo = (x.u + 0x7FFFu + ((x.u >> 16) & 1u)) >> 16;
    unsigned hi = (y.u + 0x7FFFu + ((y.u >> 16) & 1u)) & 0xFFFF0000u;
    return lo | hi;
}

__device__ __forceinline__ unsigned short f2bf1(float a) {
    union { float f; unsigned u; } x;
    x.f = a;
    return (unsigned short)((x.u + 0x7FFFu + ((x.u >> 16) & 1u)) >> 16);
}

// unpack 2 bf16 (packed in one u32: low short, high short) -> 2 floats
__device__ __forceinline__ float2 bfp2(unsigned u) {
    union { unsigned u; float f; } a, b;
    a.u = u << 16;
    b.u = u & 0xFFFF0000u;
    return make_float2(a.f, b.f);
}

// ---------------- utility ----------------

__global__ void k_zero(int* __restrict__ p, int n) {
    int i = blockIdx.x * 256 + threadIdx.x;
    if (i < n) p[i] = 0;
}

// ---------------- edge sorting (counting sort by dst) ----------------

__global__ void k_hist(const int* __restrict__ dst, int* __restrict__ hist, int E) {
    int e = blockIdx.x * 256 + threadIdx.x;
    if (e < E) atomicAdd(&hist[dst[e]], 1);
}

__global__ __launch_bounds__(1024) void k_scan(const int* __restrict__ hist,
                                               int* __restrict__ off, int n) {
    __shared__ int buf[1024];
    __shared__ int carry;
    int tid = threadIdx.x;
    if (tid == 0) carry = 0;
    __syncthreads();
    for (int base = 0; base < n; base += 1024) {
        int v = (base + tid < n) ? hist[base + tid] : 0;
        buf[tid] = v;
        __syncthreads();
        int x = v;
        for (int o = 1; o < 1024; o <<= 1) {
            int t = (tid >= o) ? buf[tid - o] : 0;
            __syncthreads();
            x += t;
            buf[tid] = x;
            __syncthreads();
        }
        int c = carry;
        if (base + tid < n) off[base + tid] = c + x - v;   // exclusive
        __syncthreads();
        if (tid == 1023) carry = c + buf[1023];
        __syncthreads();
    }
    if (tid == 0) off[n] = carry;
}

__global__ void k_scatter(const int* __restrict__ src, const int* __restrict__ dst,
                          const int* __restrict__ off, int* __restrict__ cursor,
                          int* __restrict__ srcS, int* __restrict__ dstS, int E) {
    int e = blockIdx.x * 256 + threadIdx.x;
    if (e < E) {
        int d = dst[e];
        int pos = off[d] + atomicAdd(&cursor[d], 1);
        srcS[pos] = src[e];
        dstS[pos] = d;
    }
}

// ---------------- weight prep (transpose + cvt to bf16) ----------------

__global__ void k_wcat(const float* __restrict__ Wq, const float* __restrict__ Wk,
                       const float* __restrict__ Wv, const float* __restrict__ Ws,
                       short* __restrict__ Wt) {
    int idx = blockIdx.x * 256 + threadIdx.x;   // l*2^20 + n*512 + k
    int k = idx & 511;
    int nf = (idx >> 9) & 2047;
    int l = idx >> 20;
    int sel = nf >> 9, nn = nf & 511;
    const float* W = (sel == 0) ? Wq : (sel == 1) ? Wk : (sel == 2) ? Wv : Ws;
    float v = W[((size_t)l * 512 + k) * 512 + nn];
    Wt[idx] = (short)f2bf1(v);
}

// generic W[K][N] fp32 -> Wt[N][K] bf16
__global__ void k_tr(const float* __restrict__ W, short* __restrict__ Wt, int K, int N) {
    int k = blockIdx.x * 256 + threadIdx.x;
    int n = blockIdx.y;
    if (k < K) Wt[(size_t)n * K + k] = (short)f2bf1(W[(size_t)k * N + n]);
}

__global__ void k_bcat(const float* __restrict__ bq, const float* __restrict__ bk,
                       const float* __restrict__ bv, const float* __restrict__ bs,
                       float* __restrict__ bcat) {
    int idx = blockIdx.x * 256 + threadIdx.x;
    if (idx >= L_LAYERS * 2048) return;
    int l = idx >> 11, n = idx & 2047;
    int sel = n >> 9, nn = n & 511;
    const float* b = (sel == 0) ? bq : (sel == 1) ? bk : (sel == 2) ? bv : bs;
    bcat[idx] = b[l * 512 + nn];
}

__global__ void k_bdual(const float* __restrict__ sb, const float* __restrict__ ab,
                        float* __restrict__ bd) {
    int idx = blockIdx.x * 256 + threadIdx.x;
    if (idx < 1024) bd[idx] = (idx < 512) ? sb[idx] : ab[idx - 512];
}

// ---------------- bf16 MFMA GEMM, A fp32 (cvt on stage), Bt bf16 [N][K] ----------------
// C = act(A*Bt^T + bias); C fp32 (obf=0) or bf16 (obf=1). 128x128 tile, BK=32.
// LDS rows padded to 40 shorts (80 B): 16-row ds_read_b128 -> 2 lanes/bank (free).

__global__ __launch_bounds__(256) void gemm_a32(
    const float* __restrict__ A, int lda,
    const short* __restrict__ Bt,
    const float* __restrict__ bias,
    void* __restrict__ Cv, int ldc,
    int M, int N, int K, int act, int obf) {
    __shared__ __align__(16) short As[128][40];
    __shared__ __align__(16) short Bs[128][40];
    const int tid = threadIdx.x;
    const int lane = tid & 63;
    const int wave = tid >> 6;
    const int wr = (wave >> 1) * 64;
    const int wc = (wave & 1) * 64;
    const int l16 = lane & 15;
    const int quad = lane >> 4;
    const int row0 = blockIdx.x * 128;
    const int col0 = blockIdx.y * 128;
    const int sr = tid >> 2;
    const int sk = (tid & 3) * 8;

    f32x4 acc[4][4];
#pragma unroll
    for (int i = 0; i < 4; ++i)
#pragma unroll
        for (int j = 0; j < 4; ++j)
            acc[i][j] = f32x4{0.f, 0.f, 0.f, 0.f};

    for (int kb = 0; kb < K; kb += 32) {
#pragma unroll
        for (int hh = 0; hh < 2; ++hh) {
            int r = sr + hh * 64;
            int gr = row0 + r;
            float4 a0, a1;
            if (gr < M) {
                const float* p = A + (size_t)gr * lda + kb + sk;
                a0 = *(const float4*)p;
                a1 = *(const float4*)(p + 4);
            } else {
                a0 = make_float4(0.f, 0.f, 0.f, 0.f);
                a1 = make_float4(0.f, 0.f, 0.f, 0.f);
            }
            uint4 av;
            av.x = f2bf2(a0.x, a0.y);
            av.y = f2bf2(a0.z, a0.w);
            av.z = f2bf2(a1.x, a1.y);
            av.w = f2bf2(a1.z, a1.w);
            *(uint4*)&As[r][sk] = av;
            const short* bp = Bt + (size_t)(col0 + r) * K + kb + sk;
            *(uint4*)&Bs[r][sk] = *(const uint4*)bp;
        }
        __syncthreads();
        bf16x8 af[4], bfr[4];
#pragma unroll
        for (int i = 0; i < 4; ++i)
            af[i] = *(const bf16x8*)&As[wr + i * 16 + l16][quad * 8];
#pragma unroll
        for (int j = 0; j < 4; ++j)
            bfr[j] = *(const bf16x8*)&Bs[wc + j * 16 + l16][quad * 8];
#pragma unroll
        for (int i = 0; i < 4; ++i)
#pragma unroll
            for (int j = 0; j < 4; ++j)
                acc[i][j] = __builtin_amdgcn_mfma_f32_16x16x32_bf16(af[i], bfr[j], acc[i][j], 0, 0, 0);
        __syncthreads();
    }
    float* Cf = (float*)Cv;
    short* Cs = (short*)Cv;
#pragma unroll
    for (int i = 0; i < 4; ++i) {
        int rbase = row0 + wr + i * 16 + quad * 4;
#pragma unroll
        for (int j = 0; j < 4; ++j) {
            int c = col0 + wc + j * 16 + l16;
            float bv = bias ? bias[c] : 0.0f;
#pragma unroll
            for (int rg = 0; rg < 4; ++rg) {
                int gr = rbase + rg;
                if (gr < M) {
                    float v = acc[i][j][rg] + bv;
                    if (act) v = gelu1(v);
                    if (obf) Cs[(size_t)gr * ldc + c] = (short)f2bf1(v);
                    else     Cf[(size_t)gr * ldc + c] = v;
                }
            }
        }
    }
}

// ---------------- bf16 MFMA GEMM, A bf16, C bf16, no bias/act (for t = z @ W) ----------------

__global__ __launch_bounds__(256) void gemm_abf(
    const short* __restrict__ A, int lda,
    const short* __restrict__ Bt,
    short* __restrict__ C, int ldc,
    int M, int N, int K) {
    __shared__ __align__(16) short As[128][40];
    __shared__ __align__(16) short Bs[128][40];
    const int tid = threadIdx.x;
    const int lane = tid & 63;
    const int wave = tid >> 6;
    const int wr = (wave >> 1) * 64;
    const int wc = (wave & 1) * 64;
    const int l16 = lane & 15;
    const int quad = lane >> 4;
    const int row0 = blockIdx.x * 128;
    const int col0 = blockIdx.y * 128;
    const int sr = tid >> 2;
    const int sk = (tid & 3) * 8;

    f32x4 acc[4][4];
#pragma unroll
    for (int i = 0; i < 4; ++i)
#pragma unroll
        for (int j = 0; j < 4; ++j)
            acc[i][j] = f32x4{0.f, 0.f, 0.f, 0.f};

    for (int kb = 0; kb < K; kb += 32) {
#pragma unroll
        for (int hh = 0; hh < 2; ++hh) {
            int r = sr + hh * 64;
            int gr = row0 + r;
            uint4 av = make_uint4(0u, 0u, 0u, 0u);
            if (gr < M) av = *(const uint4*)(A + (size_t)gr * lda + kb + sk);
            *(uint4*)&As[r][sk] = av;
            *(uint4*)&Bs[r][sk] = *(const uint4*)(Bt + (size_t)(col0 + r) * K + kb + sk);
        }
        __syncthreads();
        bf16x8 af[4], bfr[4];
#pragma unroll
        for (int i = 0; i < 4; ++i)
            af[i] = *(const bf16x8*)&As[wr + i * 16 + l16][quad * 8];
#pragma unroll
        for (int j = 0; j < 4; ++j)
            bfr[j] = *(const bf16x8*)&Bs[wc + j * 16 + l16][quad * 8];
#pragma unroll
        for (int i = 0; i < 4; ++i)
#pragma unroll
            for (int j = 0; j < 4; ++j)
                acc[i][j] = __builtin_amdgcn_mfma_f32_16x16x32_bf16(af[i], bfr[j], acc[i][j], 0, 0, 0);
        __syncthreads();
    }
#pragma unroll
    for (int i = 0; i < 4; ++i) {
        int rbase = row0 + wr + i * 16 + quad * 4;
#pragma unroll
        for (int j = 0; j < 4; ++j) {
            int c = col0 + wc + j * 16 + l16;
#pragma unroll
            for (int rg = 0; rg < 4; ++rg) {
                int gr = rbase + rg;
                if (gr < M) C[(size_t)gr * ldc + c] = (short)f2bf1(acc[i][j][rg]);
            }
        }
    }
}

// ---------------- fused gate: pair-features -> gW1 -> gelu -> .gW2 -> sigmoid -> combine ----
// One 512-thread block computes the FULL 128x512 hidden tile: A built once per K-step
// in LDS (shared by 8 waves), B fragments read directly from global (gW1^T is 2 MB,
// L2-resident). Epilogue reduces hidden.gW2 per row in LDS and writes out[] directly.
// wave w: row group (w>>2)*64, col group (w&3)*128. Wave tile 64x128 -> acc[4][8].

__global__ __launch_bounds__(512, 2) void gemm_gate(
    const short* __restrict__ z,
    const int* __restrict__ pi, const int* __restrict__ pj, int P,
    const short* __restrict__ Bt,    // gW1^T [512][2048]
    const float* __restrict__ gb1,
    const float* __restrict__ gW2,
    const float* __restrict__ gb2,
    const float* __restrict__ ssyn,
    const float* __restrict__ sant,
    float* __restrict__ out) {
    __shared__ __align__(16) short As[128][40];
    __shared__ int iArr[128];
    __shared__ int jArr[128];
    __shared__ float rowsum[128];
    const int tid = threadIdx.x;
    const int lane = tid & 63;
    const int wave = tid >> 6;
    const int wr = (wave >> 2) * 64;    // row group 0/64
    const int wc = (wave & 3) * 128;    // col group 0..3
    const int l16 = lane & 15;
    const int quad = lane >> 4;
    const int row0 = blockIdx.x * 128;
    const int sr = tid >> 2;            // 0..127: LDS row this thread stages
    const int sk = (tid & 3) * 8;       // k-offset within 32-wide tile

    if (tid < 128) {
        int p = row0 + tid;
        int ok = (p < P);
        iArr[tid] = ok ? pi[p] : 0;
        jArr[tid] = ok ? pj[p] : 0;
        rowsum[tid] = 0.0f;
    }
    __syncthreads();
    const int ii = iArr[sr];
    const int jj = jArr[sr];
    const short* zi = z + (size_t)ii * 1024 + sk;
    const short* zj = z + (size_t)jj * 1024 + sk;
    // per-wave B base: col = wc + j*16 + l16, k = kb + quad*8
    const short* bbase = Bt + (size_t)(wc + l16) * 2048 + quad * 8;

    f32x4 acc[4][8];
#pragma unroll
    for (int i = 0; i < 4; ++i)
#pragma unroll
        for (int j = 0; j < 8; ++j)
            acc[i][j] = f32x4{0.f, 0.f, 0.f, 0.f};

    for (int kb = 0; kb < 2048; kb += 32) {
        int seg = kb >> 9;
        int colbase = ((seg >> 1) << 9) + (kb & 511);
        int mulmode = seg & 1;
        uint4 xu = *(const uint4*)(zi + colbase);
        uint4 yu = *(const uint4*)(zj + colbase);
        float2 x0 = bfp2(xu.x), x1 = bfp2(xu.y), x2 = bfp2(xu.z), x3 = bfp2(xu.w);
        float2 y0 = bfp2(yu.x), y1 = bfp2(yu.y), y2 = bfp2(yu.z), y3 = bfp2(yu.w);
        float f[8];
        if (mulmode) {
            f[0] = x0.x * y0.x; f[1] = x0.y * y0.y;
            f[2] = x1.x * y1.x; f[3] = x1.y * y1.y;
            f[4] = x2.x * y2.x; f[5] = x2.y * y2.y;
            f[6] = x3.x * y3.x; f[7] = x3.y * y3.y;
        } else {
            f[0] = fabsf(x0.x - y0.x); f[1] = fabsf(x0.y - y0.y);
            f[2] = fabsf(x1.x - y1.x); f[3] = fabsf(x1.y - y1.y);
            f[4] = fabsf(x2.x - y2.x); f[5] = fabsf(x2.y - y2.y);
            f[6] = fabsf(x3.x - y3.x); f[7] = fabsf(x3.y - y3.y);
        }
        uint4 av;
        av.x = f2bf2(f[0], f[1]);
        av.y = f2bf2(f[2], f[3]);
        av.z = f2bf2(f[4], f[5]);
        av.w = f2bf2(f[6], f[7]);
        *(uint4*)&As[sr][sk] = av;
        __syncthreads();
        bf16x8 af[4], bfr[8];
#pragma unroll
        for (int i = 0; i < 4; ++i)
            af[i] = *(const bf16x8*)&As[wr + i * 16 + l16][quad * 8];
#pragma unroll
        for (int j = 0; j < 8; ++j)
            bfr[j] = *(const bf16x8*)(bbase + (size_t)j * 16 * 2048 + kb);
#pragma unroll
        for (int i = 0; i < 4; ++i)
#pragma unroll
            for (int j = 0; j < 8; ++j)
                acc[i][j] = __builtin_amdgcn_mfma_f32_16x16x32_bf16(af[i], bfr[j], acc[i][j], 0, 0, 0);
        __syncthreads();
    }
    // epilogue: rowwise sum of gelu(acc + gb1) * gW2
#pragma unroll
    for (int i = 0; i < 4; ++i) {
#pragma unroll
        for (int rg = 0; rg < 4; ++rg) {
            float partial = 0.f;
#pragma unroll
            for (int j = 0; j < 8; ++j) {
                int c = wc + j * 16 + l16;
                partial += gelu1(acc[i][j][rg] + gb1[c]) * gW2[c];
            }
            partial += __shfl_xor(partial, 1);
            partial += __shfl_xor(partial, 2);
            partial += __shfl_xor(partial, 4);
            partial += __shfl_xor(partial, 8);
            if (l16 == 0)
                atomicAdd(&rowsum[wr + i * 16 + quad * 4 + rg], partial);
        }
    }
    __syncthreads();
    if (tid < 128) {
        int p = row0 + tid;
        if (p < P) {
            float s = 1.0f / (1.0f + __expf(-(rowsum[tid] + gb2[0])));
            out[p] = s * sant[p] - (1.0f - s) * ssyn[p];
        }
    }
}

// ---------------- per-layer edge kernels (bf16 node tensors) ----------------

// qk bf16 [Nn][1024]: q cols 0..511, k cols 512..1023. One wave per edge.
__global__ __launch_bounds__(256) void k_logits(const short* __restrict__ qk,
                                                const int* __restrict__ srcS,
                                                const int* __restrict__ dstS,
                                                float* __restrict__ logits, int E) {
    int pos = blockIdx.x * 4 + (threadIdx.x >> 6);
    if (pos >= E) return;
    int lane = threadIdx.x & 63;
    int head = lane >> 4, li = lane & 15;
    int d = dstS[pos], s = srcS[pos];
    uint4 qv = *(const uint4*)(qk + (size_t)d * 1024 + head * 128 + li * 8);
    uint4 kv = *(const uint4*)(qk + (size_t)s * 1024 + 512 + head * 128 + li * 8);
    float2 q0 = bfp2(qv.x), q1 = bfp2(qv.y), q2 = bfp2(qv.z), q3 = bfp2(qv.w);
    float2 k0 = bfp2(kv.x), k1 = bfp2(kv.y), k2 = bfp2(kv.z), k3 = bfp2(kv.w);
    float dot = q0.x * k0.x + q0.y * k0.y + q1.x * k1.x + q1.y * k1.y +
                q2.x * k2.x + q2.y * k2.y + q3.x * k3.x + q3.y * k3.y;
    dot += __shfl_xor(dot, 1);
    dot += __shfl_xor(dot, 2);
    dot += __shfl_xor(dot, 4);
    dot += __shfl_xor(dot, 8);
    if (li == 0) logits[(size_t)pos * 4 + head] = dot * 0.08838834764831845f;
}

// in-place segment softmax per (node, head); one wave per node, 16 lanes per head
__global__ __launch_bounds__(256) void k_softmax(float* __restrict__ lg,
                                                 const int* __restrict__ off, int Nn) {
    int n = blockIdx.x * 4 + (threadIdx.x >> 6);
    if (n >= Nn) return;
    int lane = threadIdx.x & 63;
    int head = lane >> 4, li = lane & 15;
    int st = off[n], en = off[n + 1];
    if (st >= en) return;
    float m = -3.4e38f;
    for (int pos = st + li; pos < en; pos += 16)
        m = fmaxf(m, lg[(size_t)pos * 4 + head]);
    m = fmaxf(m, __shfl_xor(m, 1));
    m = fmaxf(m, __shfl_xor(m, 2));
    m = fmaxf(m, __shfl_xor(m, 4));
    m = fmaxf(m, __shfl_xor(m, 8));
    float s = 0.f;
    for (int pos = st + li; pos < en; pos += 16)
        s += __expf(lg[(size_t)pos * 4 + head] - m);
    s += __shfl_xor(s, 1);
    s += __shfl_xor(s, 2);
    s += __shfl_xor(s, 4);
    s += __shfl_xor(s, 8);
    float rinv = 1.0f / s;
    for (int pos = st + li; pos < en; pos += 16)
        lg[(size_t)pos * 4 + head] = __expf(lg[(size_t)pos * 4 + head] - m) * rinv;
}

// vs bf16 [Nn][1024]: v cols 0..511, s cols 512..1023.
// out = sum alpha*v[src] + s ; gelu ; h = LN(h + out); one block (128 thr) per node
__global__ __launch_bounds__(128) void k_aggregate(const short* __restrict__ vs,
                                                   const int* __restrict__ srcS,
                                                   const int* __restrict__ off,
                                                   const float* __restrict__ alpha,
                                                   float* __restrict__ h,
                                                   const float* __restrict__ lng,
                                                   const float* __restrict__ lnb, int Nn) {
    int n = blockIdx.x;
    int t = threadIdx.x;
    int ch = t * 4;
    int head = t >> 5;
    float ax = 0.f, ay = 0.f, az = 0.f, aw = 0.f;
    int st = off[n], en = off[n + 1];
    for (int pos = st; pos < en; ++pos) {
        float a = alpha[(size_t)pos * 4 + head];
        uint2 vv = *(const uint2*)(vs + (size_t)srcS[pos] * 1024 + ch);
        float2 v01 = bfp2(vv.x), v23 = bfp2(vv.y);
        ax += a * v01.x; ay += a * v01.y; az += a * v23.x; aw += a * v23.y;
    }
    uint2 su = *(const uint2*)(vs + (size_t)n * 1024 + 512 + ch);
    float2 s01 = bfp2(su.x), s23 = bfp2(su.y);
    float ox = gelu1(ax + s01.x);
    float oy = gelu1(ay + s01.y);
    float oz = gelu1(az + s23.x);
    float ow = gelu1(aw + s23.y);
    const float4 hv = *(const float4*)(h + (size_t)n * 512 + ch);
    float rx = hv.x + ox, ry = hv.y + oy, rz = hv.z + oz, rw = hv.w + ow;
    float sum = rx + ry + rz + rw;
    float ssq = rx * rx + ry * ry + rz * rz + rw * rw;
    int lane = t & 63, wv = t >> 6;
    for (int o = 32; o; o >>= 1) {
        sum += __shfl_xor(sum, o);
        ssq += __shfl_xor(ssq, o);
    }
    __shared__ float red[4];
    if (lane == 0) { red[wv] = sum; red[2 + wv] = ssq; }
    __syncthreads();
    float tot = red[0] + red[1], tot2 = red[2] + red[3];
    float mean = tot * (1.0f / 512.0f);
    float var = tot2 * (1.0f / 512.0f) - mean * mean;
    float inv = rsqrtf(var + 1e-5f);
    const float4 g4 = *(const float4*)(lng + ch);
    const float4 b4 = *(const float4*)(lnb + ch);
    float4 o4;
    o4.x = (rx - mean) * inv * g4.x + b4.x;
    o4.y = (ry - mean) * inv * g4.y + b4.y;
    o4.z = (rz - mean) * inv * g4.z + b4.z;
    o4.w = (rw - mean) * inv * g4.w + b4.w;
    *(float4*)(h + (size_t)n * 512 + ch) = o4;
}

// ---------------- pair bilinear scores (bf16 z,t) ----------------

__global__ __launch_bounds__(256) void k_pairscore(const short* __restrict__ z,
                                                   const short* __restrict__ t,
                                                   const int* __restrict__ pi,
                                                   const int* __restrict__ pj,
                                                   float* __restrict__ ssyn,
                                                   float* __restrict__ sant, int P) {
    int p = blockIdx.x * 4 + (threadIdx.x >> 6);
    if (p >= P) return;
    int lane = threadIdx.x & 63;
    int i = pi[p], j = pj[p];
    uint4 a = *(const uint4*)(t + (size_t)i * 1024 + lane * 8);
    uint4 b = *(const uint4*)(z + (size_t)j * 1024 + lane * 8);
    float2 a0 = bfp2(a.x), a1 = bfp2(a.y), a2 = bfp2(a.z), a3 = bfp2(a.w);
    float2 b0 = bfp2(b.x), b1 = bfp2(b.y), b2 = bfp2(b.z), b3 = bfp2(b.w);
    float ds = a0.x * b0.x + a0.y * b0.y + a1.x * b1.x + a1.y * b1.y +
               a2.x * b2.x + a2.y * b2.y + a3.x * b3.x + a3.y * b3.y;
    uint4 c = *(const uint4*)(t + (size_t)i * 1024 + 512 + lane * 8);
    uint4 d = *(const uint4*)(z + (size_t)j * 1024 + 512 + lane * 8);
    float2 c0 = bfp2(c.x), c1 = bfp2(c.y), c2 = bfp2(c.z), c3 = bfp2(c.w);
    float2 d0 = bfp2(d.x), d1 = bfp2(d.y), d2 = bfp2(d.z), d3 = bfp2(d.w);
    float da = c0.x * d0.x + c0.y * d0.y + c1.x * d1.x + c1.y * d1.y +
               c2.x * d2.x + c2.y * d2.y + c3.x * d3.x + c3.y * d3.y;
    for (int o = 32; o; o >>= 1) {
        ds += __shfl_xor(ds, o);
        da += __shfl_xor(da, o);
    }
    if (lane == 0) { ssyn[p] = ds; sant[p] = da; }
}

// ---------------- host ----------------

extern "C" void kernel_launch(void* const* d_in, const int* in_sizes, int n_in,
                              void* d_out, int out_size, void* d_ws, size_t ws_size,
                              hipStream_t stream) {
    const float* x = (const float*)d_in[0];
    const int* ei = (const int*)d_in[1];
    const int* pe = (const int*)d_in[2];
    const float* mixer_W = (const float*)d_in[3];
    const float* mixer_b = (const float*)d_in[4];
    const float* Wq = (const float*)d_in[5];
    const float* bq = (const float*)d_in[6];
    const float* Wk = (const float*)d_in[7];
    const float* bk = (const float*)d_in[8];
    const float* Wv = (const float*)d_in[9];
    const float* bv = (const float*)d_in[10];
    const float* Ws = (const float*)d_in[11];
    const float* bs = (const float*)d_in[12];
    const float* ln_g = (const float*)d_in[13];
    const float* ln_b = (const float*)d_in[14];
    const float* syn_W = (const float*)d_in[15];
    const float* syn_b = (const float*)d_in[16];
    const float* ant_W = (const float*)d_in[17];
    const float* ant_b = (const float*)d_in[18];
    const float* W_syn = (const float*)d_in[19];
    const float* W_ant = (const float*)d_in[20];
    const float* gW1 = (const float*)d_in[21];
    const float* gb1 = (const float*)d_in[22];
    const float* gW2 = (const float*)d_in[23];
    const float* gb2 = (const float*)d_in[24];
    float* out = (float*)d_out;

    const int Nn = in_sizes[0] / 768;  // 20000
    const int E = in_sizes[1] / 2;     // 320000
    const int P = in_sizes[2] / 2;     // 100000

    char* w = (char*)d_ws;
    auto alloc = [&](size_t bytes) -> char* {
        char* p = w;
        w += (bytes + 255) & ~(size_t)255;
        return p;
    };
    float* h = (float*)alloc((size_t)Nn * 512 * 4);           // 41 MB
    short* B1 = (short*)alloc((size_t)Nn * 1024 * 2);         // 41 MB: qk / vs, later z
    short* B2 = (short*)alloc((size_t)Nn * 1024 * 2);         // 41 MB: t
    float* logits = (float*)alloc((size_t)E * 4 * 4);         // 5.1 MB; alpha in-place
    int* srcS = (int*)alloc((size_t)E * 4);
    int* dstS = (int*)alloc((size_t)E * 4);
    int* hist = (int*)alloc((size_t)Nn * 2 * 4);
    int* cursor = hist + Nn;
    int* offs = (int*)alloc((size_t)(Nn + 1) * 4);
    short* mixWt = (short*)alloc((size_t)512 * 768 * 2);
    short* wcat = (short*)alloc((size_t)L_LAYERS * 2048 * 512 * 2);
    short* dualWt = (short*)alloc((size_t)1024 * 512 * 2);
    short* bilWt = (short*)alloc((size_t)1024 * 512 * 2);
    short* gw1t = (short*)alloc((size_t)512 * 2048 * 2);
    float* bcat = (float*)alloc((size_t)L_LAYERS * 2048 * 4);
    float* bdual = (float*)alloc((size_t)1024 * 4);
    // phase-3 overlays onto dead logits region
    float* ssyn = logits;
    float* sant = logits + P;

    k_zero<<<(2 * Nn + 255) / 256, 256, 0, stream>>>(hist, 2 * Nn);
    k_hist<<<(E + 255) / 256, 256, 0, stream>>>(ei + E, hist, E);
    k_scan<<<1, 1024, 0, stream>>>(hist, offs, Nn);
    k_scatter<<<(E + 255) / 256, 256, 0, stream>>>(ei, ei + E, offs, cursor, srcS, dstS, E);

    k_wcat<<<(L_LAYERS * 2048 * 512) / 256, 256, 0, stream>>>(Wq, Wk, Wv, Ws, wcat);
    k_tr<<<dim3(3, 512), 256, 0, stream>>>(mixer_W, mixWt, 768, 512);
    k_tr<<<dim3(2, 512), 256, 0, stream>>>(syn_W, dualWt, 512, 512);
    k_tr<<<dim3(2, 512), 256, 0, stream>>>(ant_W, dualWt + 512 * 512, 512, 512);
    k_tr<<<dim3(2, 512), 256, 0, stream>>>(W_syn, bilWt, 512, 512);
    k_tr<<<dim3(2, 512), 256, 0, stream>>>(W_ant, bilWt + 512 * 512, 512, 512);
    k_tr<<<dim3(8, 512), 256, 0, stream>>>(gW1, gw1t, 2048, 512);
    k_bcat<<<48, 256, 0, stream>>>(bq, bk, bv, bs, bcat);
    k_bdual<<<4, 256, 0, stream>>>(syn_b, ant_b, bdual);

    const int mtiles = (Nn + 127) / 128;  // 157
    // mixer: h = gelu(x @ mixer_W + b), fp32 out
    gemm_a32<<<dim3(mtiles, 4), 256, 0, stream>>>(x, 768, mixWt, mixer_b, h, 512,
                                                  Nn, 512, 768, 1, 0);

    for (int l = 0; l < L_LAYERS; ++l) {
        const short* wl = wcat + (size_t)l * 2048 * 512;
        const float* bl = bcat + l * 2048;
        // q|k -> B1 bf16
        gemm_a32<<<dim3(mtiles, 8), 256, 0, stream>>>(h, 512, wl, bl, B1, 1024,
                                                      Nn, 1024, 512, 0, 1);
        k_logits<<<(E + 3) / 4, 256, 0, stream>>>(B1, srcS, dstS, logits, E);
        k_softmax<<<(Nn + 3) / 4, 256, 0, stream>>>(logits, offs, Nn);
        // v|s -> B1 bf16 (overwrites qk)
        gemm_a32<<<dim3(mtiles, 8), 256, 0, stream>>>(h, 512, wl + (size_t)1024 * 512,
                                                      bl + 1024, B1, 1024, Nn, 1024, 512, 0, 1);
        k_aggregate<<<Nn, 128, 0, stream>>>(B1, srcS, offs, logits, h,
                                            ln_g + l * 512, ln_b + l * 512, Nn);
    }

    // z = gelu(h @ [syn_W|ant_W] + b) -> B1 bf16 [Nn][1024]
    gemm_a32<<<dim3(mtiles, 8), 256, 0, stream>>>(h, 512, dualWt, bdual, B1, 1024,
                                                  Nn, 1024, 512, 1, 1);
    // t = z @ W -> B2 bf16 [Nn][1024]
    gemm_abf<<<dim3(mtiles, 4), 256, 0, stream>>>(B1, 1024, bilWt, B2, 1024, Nn, 512, 512);
    gemm_abf<<<dim3(mtiles, 4), 256, 0, stream>>>(B1 + 512, 1024, bilWt + 512 * 512,
                                                  B2 + 512, 1024, Nn, 512, 512);

    k_pairscore<<<(P + 3) / 4, 256, 0, stream>>>(B1, B2, pe, pe + P, ssyn, sant, P);

    // fused gate MLP + final combine
    gemm_gate<<<(P + 127) / 128, 512, 0, stream>>>(B1, pe, pe + P, P, gw1t, gb1, gW2, gb2,
                                                   ssyn, sant, out);
}

// Round 4
// 2515.587 us; speedup vs baseline: 1.1674x; 1.1674x over previous
//
#include <hip/hip_runtime.h>
#include <cstdint>

#define L_LAYERS 6

typedef __attribute__((ext_vector_type(8))) short bf16x8;
typedef __attribute__((ext_vector_type(4))) float f32x4;

__device__ __forceinline__ float gelu1(float v) {
    return 0.5f * v * (1.0f + erff(v * 0.7071067811865475f));
}

// pack two fp32 into two bf16 (round-nearest-even), low|high
__device__ __forceinline__ unsigned int f2bf2(float a, float b) {
    union { float f; unsigned u; } x, y;
    x.f = a; y.f = b;
    unsigned lo = (x.u + 0x7FFFu + ((x.u >> 16) & 1u)) >> 16;
    unsigned hi = (y.u + 0x7FFFu + ((y.u >> 16) & 1u)) & 0xFFFF0000u;
    return lo | hi;
}

__device__ __forceinline__ unsigned short f2bf1(float a) {
    union { float f; unsigned u; } x;
    x.f = a;
    return (unsigned short)((x.u + 0x7FFFu + ((x.u >> 16) & 1u)) >> 16);
}

// unpack 2 bf16 (packed in one u32: low short, high short) -> 2 floats
__device__ __forceinline__ float2 bfp2(unsigned u) {
    union { unsigned u; float f; } a, b;
    a.u = u << 16;
    b.u = u & 0xFFFF0000u;
    return make_float2(a.f, b.f);
}

// ---------------- utility ----------------

__global__ void k_zero(int* __restrict__ p, int n) {
    int i = blockIdx.x * 256 + threadIdx.x;
    if (i < n) p[i] = 0;
}

// ---------------- edge sorting (counting sort by dst) ----------------

__global__ void k_hist(const int* __restrict__ dst, int* __restrict__ hist, int E) {
    int e = blockIdx.x * 256 + threadIdx.x;
    if (e < E) atomicAdd(&hist[dst[e]], 1);
}

__global__ __launch_bounds__(1024) void k_scan(const int* __restrict__ hist,
                                               int* __restrict__ off, int n) {
    __shared__ int buf[1024];
    __shared__ int carry;
    int tid = threadIdx.x;
    if (tid == 0) carry = 0;
    __syncthreads();
    for (int base = 0; base < n; base += 1024) {
        int v = (base + tid < n) ? hist[base + tid] : 0;
        buf[tid] = v;
        __syncthreads();
        int x = v;
        for (int o = 1; o < 1024; o <<= 1) {
            int t = (tid >= o) ? buf[tid - o] : 0;
            __syncthreads();
            x += t;
            buf[tid] = x;
            __syncthreads();
        }
        int c = carry;
        if (base + tid < n) off[base + tid] = c + x - v;   // exclusive
        __syncthreads();
        if (tid == 1023) carry = c + buf[1023];
        __syncthreads();
    }
    if (tid == 0) off[n] = carry;
}

__global__ void k_scatter(const int* __restrict__ src, const int* __restrict__ dst,
                          const int* __restrict__ off, int* __restrict__ cursor,
                          int* __restrict__ srcS, int* __restrict__ dstS, int E) {
    int e = blockIdx.x * 256 + threadIdx.x;
    if (e < E) {
        int d = dst[e];
        int pos = off[d] + atomicAdd(&cursor[d], 1);
        srcS[pos] = src[e];
        dstS[pos] = d;
    }
}

// ---------------- weight prep (transpose + cvt to bf16) ----------------

__global__ void k_wcat(const float* __restrict__ Wq, const float* __restrict__ Wk,
                       const float* __restrict__ Wv, const float* __restrict__ Ws,
                       short* __restrict__ Wt) {
    int idx = blockIdx.x * 256 + threadIdx.x;   // l*2^20 + n*512 + k
    int k = idx & 511;
    int nf = (idx >> 9) & 2047;
    int l = idx >> 20;
    int sel = nf >> 9, nn = nf & 511;
    const float* W = (sel == 0) ? Wq : (sel == 1) ? Wk : (sel == 2) ? Wv : Ws;
    float v = W[((size_t)l * 512 + k) * 512 + nn];
    Wt[idx] = (short)f2bf1(v);
}

// generic W[K][N] fp32 -> Wt[N][K] bf16
__global__ void k_tr(const float* __restrict__ W, short* __restrict__ Wt, int K, int N) {
    int k = blockIdx.x * 256 + threadIdx.x;
    int n = blockIdx.y;
    if (k < K) Wt[(size_t)n * K + k] = (short)f2bf1(W[(size_t)k * N + n]);
}

__global__ void k_bcat(const float* __restrict__ bq, const float* __restrict__ bk,
                       const float* __restrict__ bv, const float* __restrict__ bs,
                       float* __restrict__ bcat) {
    int idx = blockIdx.x * 256 + threadIdx.x;
    if (idx >= L_LAYERS * 2048) return;
    int l = idx >> 11, n = idx & 2047;
    int sel = n >> 9, nn = n & 511;
    const float* b = (sel == 0) ? bq : (sel == 1) ? bk : (sel == 2) ? bv : bs;
    bcat[idx] = b[l * 512 + nn];
}

__global__ void k_bdual(const float* __restrict__ sb, const float* __restrict__ ab,
                        float* __restrict__ bd) {
    int idx = blockIdx.x * 256 + threadIdx.x;
    if (idx < 1024) bd[idx] = (idx < 512) ? sb[idx] : ab[idx - 512];
}

// ---------------- bf16 MFMA GEMM, A fp32 (cvt on stage), Bt bf16 [N][K] ----------------
// C = act(A*Bt^T + bias); C fp32 (obf=0) or bf16 (obf=1). 128x128 tile, BK=32.
// LDS rows padded to 40 shorts (80 B): 16-row ds_read_b128 -> 2 lanes/bank (free).

__global__ __launch_bounds__(256) void gemm_a32(
    const float* __restrict__ A, int lda,
    const short* __restrict__ Bt,
    const float* __restrict__ bias,
    void* __restrict__ Cv, int ldc,
    int M, int N, int K, int act, int obf) {
    __shared__ __align__(16) short As[128][40];
    __shared__ __align__(16) short Bs[128][40];
    const int tid = threadIdx.x;
    const int lane = tid & 63;
    const int wave = tid >> 6;
    const int wr = (wave >> 1) * 64;
    const int wc = (wave & 1) * 64;
    const int l16 = lane & 15;
    const int quad = lane >> 4;
    const int row0 = blockIdx.x * 128;
    const int col0 = blockIdx.y * 128;
    const int sr = tid >> 2;
    const int sk = (tid & 3) * 8;

    f32x4 acc[4][4];
#pragma unroll
    for (int i = 0; i < 4; ++i)
#pragma unroll
        for (int j = 0; j < 4; ++j)
            acc[i][j] = f32x4{0.f, 0.f, 0.f, 0.f};

    for (int kb = 0; kb < K; kb += 32) {
#pragma unroll
        for (int hh = 0; hh < 2; ++hh) {
            int r = sr + hh * 64;
            int gr = row0 + r;
            float4 a0, a1;
            if (gr < M) {
                const float* p = A + (size_t)gr * lda + kb + sk;
                a0 = *(const float4*)p;
                a1 = *(const float4*)(p + 4);
            } else {
                a0 = make_float4(0.f, 0.f, 0.f, 0.f);
                a1 = make_float4(0.f, 0.f, 0.f, 0.f);
            }
            uint4 av;
            av.x = f2bf2(a0.x, a0.y);
            av.y = f2bf2(a0.z, a0.w);
            av.z = f2bf2(a1.x, a1.y);
            av.w = f2bf2(a1.z, a1.w);
            *(uint4*)&As[r][sk] = av;
            const short* bp = Bt + (size_t)(col0 + r) * K + kb + sk;
            *(uint4*)&Bs[r][sk] = *(const uint4*)bp;
        }
        __syncthreads();
        bf16x8 af[4], bfr[4];
#pragma unroll
        for (int i = 0; i < 4; ++i)
            af[i] = *(const bf16x8*)&As[wr + i * 16 + l16][quad * 8];
#pragma unroll
        for (int j = 0; j < 4; ++j)
            bfr[j] = *(const bf16x8*)&Bs[wc + j * 16 + l16][quad * 8];
#pragma unroll
        for (int i = 0; i < 4; ++i)
#pragma unroll
            for (int j = 0; j < 4; ++j)
                acc[i][j] = __builtin_amdgcn_mfma_f32_16x16x32_bf16(af[i], bfr[j], acc[i][j], 0, 0, 0);
        __syncthreads();
    }
    float* Cf = (float*)Cv;
    short* Cs = (short*)Cv;
#pragma unroll
    for (int i = 0; i < 4; ++i) {
        int rbase = row0 + wr + i * 16 + quad * 4;
#pragma unroll
        for (int j = 0; j < 4; ++j) {
            int c = col0 + wc + j * 16 + l16;
            float bv = bias ? bias[c] : 0.0f;
#pragma unroll
            for (int rg = 0; rg < 4; ++rg) {
                int gr = rbase + rg;
                if (gr < M) {
                    float v = acc[i][j][rg] + bv;
                    if (act) v = gelu1(v);
                    if (obf) Cs[(size_t)gr * ldc + c] = (short)f2bf1(v);
                    else     Cf[(size_t)gr * ldc + c] = v;
                }
            }
        }
    }
}

// ---------------- bf16 MFMA GEMM, A bf16, C bf16, no bias/act (for t = z @ W) ----------------

__global__ __launch_bounds__(256) void gemm_abf(
    const short* __restrict__ A, int lda,
    const short* __restrict__ Bt,
    short* __restrict__ C, int ldc,
    int M, int N, int K) {
    __shared__ __align__(16) short As[128][40];
    __shared__ __align__(16) short Bs[128][40];
    const int tid = threadIdx.x;
    const int lane = tid & 63;
    const int wave = tid >> 6;
    const int wr = (wave >> 1) * 64;
    const int wc = (wave & 1) * 64;
    const int l16 = lane & 15;
    const int quad = lane >> 4;
    const int row0 = blockIdx.x * 128;
    const int col0 = blockIdx.y * 128;
    const int sr = tid >> 2;
    const int sk = (tid & 3) * 8;

    f32x4 acc[4][4];
#pragma unroll
    for (int i = 0; i < 4; ++i)
#pragma unroll
        for (int j = 0; j < 4; ++j)
            acc[i][j] = f32x4{0.f, 0.f, 0.f, 0.f};

    for (int kb = 0; kb < K; kb += 32) {
#pragma unroll
        for (int hh = 0; hh < 2; ++hh) {
            int r = sr + hh * 64;
            int gr = row0 + r;
            uint4 av = make_uint4(0u, 0u, 0u, 0u);
            if (gr < M) av = *(const uint4*)(A + (size_t)gr * lda + kb + sk);
            *(uint4*)&As[r][sk] = av;
            *(uint4*)&Bs[r][sk] = *(const uint4*)(Bt + (size_t)(col0 + r) * K + kb + sk);
        }
        __syncthreads();
        bf16x8 af[4], bfr[4];
#pragma unroll
        for (int i = 0; i < 4; ++i)
            af[i] = *(const bf16x8*)&As[wr + i * 16 + l16][quad * 8];
#pragma unroll
        for (int j = 0; j < 4; ++j)
            bfr[j] = *(const bf16x8*)&Bs[wc + j * 16 + l16][quad * 8];
#pragma unroll
        for (int i = 0; i < 4; ++i)
#pragma unroll
            for (int j = 0; j < 4; ++j)
                acc[i][j] = __builtin_amdgcn_mfma_f32_16x16x32_bf16(af[i], bfr[j], acc[i][j], 0, 0, 0);
        __syncthreads();
    }
#pragma unroll
    for (int i = 0; i < 4; ++i) {
        int rbase = row0 + wr + i * 16 + quad * 4;
#pragma unroll
        for (int j = 0; j < 4; ++j) {
            int c = col0 + wc + j * 16 + l16;
#pragma unroll
            for (int rg = 0; rg < 4; ++rg) {
                int gr = rbase + rg;
                if (gr < M) C[(size_t)gr * ldc + c] = (short)f2bf1(acc[i][j][rg]);
            }
        }
    }
}

// ---------------- fused gate GEMM, pairing trick ----------------
// Feature k-space: k=c (|zs_i-zs_j|), k=512+c (zs_i*zs_j), k=1024+c (|za..|), k=1536+c (za*za)
// abs & mul segments consume the SAME z columns -> one gather builds two A-tiles,
// both accumulated (different k) into the same acc. Block tile 64 rows x 256 cols,
// 256 thr (4 waves of 64x64), grid.y=2 col-blocks. B tiles staged in LDS (coalesced).
// Epilogue: rowwise sum gelu(acc+gb1)*gW2 -> LDS -> global atomicAdd gpart[row].

__global__ __launch_bounds__(256, 3) void gemm_gate(
    const short* __restrict__ z,
    const int* __restrict__ pi, const int* __restrict__ pj, int P,
    const short* __restrict__ Bt,    // gW1^T [512][2048]
    const float* __restrict__ gb1,
    const float* __restrict__ gW2,
    float* __restrict__ gpart) {
    __shared__ __align__(16) short Aab[64][40];
    __shared__ __align__(16) short Amu[64][40];
    __shared__ __align__(16) short Bab[256][40];
    __shared__ __align__(16) short Bmu[256][40];
    __shared__ int iArr[64];
    __shared__ int jArr[64];
    __shared__ float rowsum[64];
    const int tid = threadIdx.x;
    const int lane = tid & 63;
    const int wave = tid >> 6;
    const int wc = wave * 64;
    const int l16 = lane & 15;
    const int quad = lane >> 4;
    const int row0 = blockIdx.x * 64;
    const int col0 = blockIdx.y * 256;
    const int sr = tid >> 2;        // 0..63
    const int sk = (tid & 3) * 8;

    if (tid < 64) {
        int p = row0 + tid;
        int ok = (p < P);
        iArr[tid] = ok ? pi[p] : 0;
        jArr[tid] = ok ? pj[p] : 0;
        rowsum[tid] = 0.0f;
    }
    __syncthreads();
    const short* zi = z + (size_t)iArr[sr] * 1024 + sk;
    const short* zj = z + (size_t)jArr[sr] * 1024 + sk;
    const short* bp0 = Bt + (size_t)(col0 + sr) * 2048 + sk;

    f32x4 acc[4][4];
#pragma unroll
    for (int i = 0; i < 4; ++i)
#pragma unroll
        for (int j = 0; j < 4; ++j)
            acc[i][j] = f32x4{0.f, 0.f, 0.f, 0.f};

    for (int part = 0; part < 2; ++part) {
        for (int c = 0; c < 512; c += 32) {
            // one gather feeds both abs and mul A-tiles
            uint4 xu = *(const uint4*)(zi + part * 512 + c);
            uint4 yu = *(const uint4*)(zj + part * 512 + c);
            float2 x0 = bfp2(xu.x), x1 = bfp2(xu.y), x2 = bfp2(xu.z), x3 = bfp2(xu.w);
            float2 y0 = bfp2(yu.x), y1 = bfp2(yu.y), y2 = bfp2(yu.z), y3 = bfp2(yu.w);
            uint4 aa, am;
            aa.x = f2bf2(fabsf(x0.x - y0.x), fabsf(x0.y - y0.y));
            aa.y = f2bf2(fabsf(x1.x - y1.x), fabsf(x1.y - y1.y));
            aa.z = f2bf2(fabsf(x2.x - y2.x), fabsf(x2.y - y2.y));
            aa.w = f2bf2(fabsf(x3.x - y3.x), fabsf(x3.y - y3.y));
            am.x = f2bf2(x0.x * y0.x, x0.y * y0.y);
            am.y = f2bf2(x1.x * y1.x, x1.y * y1.y);
            am.z = f2bf2(x2.x * y2.x, x2.y * y2.y);
            am.w = f2bf2(x3.x * y3.x, x3.y * y3.y);
            *(uint4*)&Aab[sr][sk] = aa;
            *(uint4*)&Amu[sr][sk] = am;
            // stage B tiles (abs: k=part*1024+c, mul: +512), rows sr,+64,+128,+192
            const short* bp = bp0 + part * 1024 + c;
#pragma unroll
            for (int hh = 0; hh < 4; ++hh) {
                const short* q = bp + (size_t)hh * 64 * 2048;
                *(uint4*)&Bab[sr + hh * 64][sk] = *(const uint4*)q;
                *(uint4*)&Bmu[sr + hh * 64][sk] = *(const uint4*)(q + 512);
            }
            __syncthreads();
            bf16x8 af[4];
#pragma unroll
            for (int i = 0; i < 4; ++i)
                af[i] = *(const bf16x8*)&Aab[i * 16 + l16][quad * 8];
#pragma unroll
            for (int j = 0; j < 4; ++j) {
                bf16x8 bf = *(const bf16x8*)&Bab[wc + j * 16 + l16][quad * 8];
#pragma unroll
                for (int i = 0; i < 4; ++i)
                    acc[i][j] = __builtin_amdgcn_mfma_f32_16x16x32_bf16(af[i], bf, acc[i][j], 0, 0, 0);
            }
#pragma unroll
            for (int i = 0; i < 4; ++i)
                af[i] = *(const bf16x8*)&Amu[i * 16 + l16][quad * 8];
#pragma unroll
            for (int j = 0; j < 4; ++j) {
                bf16x8 bf = *(const bf16x8*)&Bmu[wc + j * 16 + l16][quad * 8];
#pragma unroll
                for (int i = 0; i < 4; ++i)
                    acc[i][j] = __builtin_amdgcn_mfma_f32_16x16x32_bf16(af[i], bf, acc[i][j], 0, 0, 0);
            }
            __syncthreads();
        }
    }
    // epilogue: rowwise sum of gelu(acc + gb1) * gW2 over this block's 256 cols
#pragma unroll
    for (int i = 0; i < 4; ++i) {
#pragma unroll
        for (int rg = 0; rg < 4; ++rg) {
            float partial = 0.f;
#pragma unroll
            for (int j = 0; j < 4; ++j) {
                int cc = col0 + wc + j * 16 + l16;
                partial += gelu1(acc[i][j][rg] + gb1[cc]) * gW2[cc];
            }
            partial += __shfl_xor(partial, 1);
            partial += __shfl_xor(partial, 2);
            partial += __shfl_xor(partial, 4);
            partial += __shfl_xor(partial, 8);
            if (l16 == 0)
                atomicAdd(&rowsum[i * 16 + quad * 4 + rg], partial);
        }
    }
    __syncthreads();
    if (tid < 64 && (row0 + tid) < P)
        atomicAdd(&gpart[row0 + tid], rowsum[tid]);
}

// ---------------- per-layer edge kernels (bf16 node tensors) ----------------

// qk bf16 [Nn][1024]: q cols 0..511, k cols 512..1023. One wave per edge.
__global__ __launch_bounds__(256) void k_logits(const short* __restrict__ qk,
                                                const int* __restrict__ srcS,
                                                const int* __restrict__ dstS,
                                                float* __restrict__ logits, int E) {
    int pos = blockIdx.x * 4 + (threadIdx.x >> 6);
    if (pos >= E) return;
    int lane = threadIdx.x & 63;
    int head = lane >> 4, li = lane & 15;
    int d = dstS[pos], s = srcS[pos];
    uint4 qv = *(const uint4*)(qk + (size_t)d * 1024 + head * 128 + li * 8);
    uint4 kv = *(const uint4*)(qk + (size_t)s * 1024 + 512 + head * 128 + li * 8);
    float2 q0 = bfp2(qv.x), q1 = bfp2(qv.y), q2 = bfp2(qv.z), q3 = bfp2(qv.w);
    float2 k0 = bfp2(kv.x), k1 = bfp2(kv.y), k2 = bfp2(kv.z), k3 = bfp2(kv.w);
    float dot = q0.x * k0.x + q0.y * k0.y + q1.x * k1.x + q1.y * k1.y +
                q2.x * k2.x + q2.y * k2.y + q3.x * k3.x + q3.y * k3.y;
    dot += __shfl_xor(dot, 1);
    dot += __shfl_xor(dot, 2);
    dot += __shfl_xor(dot, 4);
    dot += __shfl_xor(dot, 8);
    if (li == 0) logits[(size_t)pos * 4 + head] = dot * 0.08838834764831845f;
}

// in-place segment softmax per (node, head); one wave per node, 16 lanes per head
__global__ __launch_bounds__(256) void k_softmax(float* __restrict__ lg,
                                                 const int* __restrict__ off, int Nn) {
    int n = blockIdx.x * 4 + (threadIdx.x >> 6);
    if (n >= Nn) return;
    int lane = threadIdx.x & 63;
    int head = lane >> 4, li = lane & 15;
    int st = off[n], en = off[n + 1];
    if (st >= en) return;
    float m = -3.4e38f;
    for (int pos = st + li; pos < en; pos += 16)
        m = fmaxf(m, lg[(size_t)pos * 4 + head]);
    m = fmaxf(m, __shfl_xor(m, 1));
    m = fmaxf(m, __shfl_xor(m, 2));
    m = fmaxf(m, __shfl_xor(m, 4));
    m = fmaxf(m, __shfl_xor(m, 8));
    float s = 0.f;
    for (int pos = st + li; pos < en; pos += 16)
        s += __expf(lg[(size_t)pos * 4 + head] - m);
    s += __shfl_xor(s, 1);
    s += __shfl_xor(s, 2);
    s += __shfl_xor(s, 4);
    s += __shfl_xor(s, 8);
    float rinv = 1.0f / s;
    for (int pos = st + li; pos < en; pos += 16)
        lg[(size_t)pos * 4 + head] = __expf(lg[(size_t)pos * 4 + head] - m) * rinv;
}

// vs bf16 [Nn][1024]: v cols 0..511, s cols 512..1023.
// out = sum alpha*v[src] + s ; gelu ; h = LN(h + out); one block (128 thr) per node
__global__ __launch_bounds__(128) void k_aggregate(const short* __restrict__ vs,
                                                   const int* __restrict__ srcS,
                                                   const int* __restrict__ off,
                                                   const float* __restrict__ alpha,
                                                   float* __restrict__ h,
                                                   const float* __restrict__ lng,
                                                   const float* __restrict__ lnb, int Nn) {
    int n = blockIdx.x;
    int t = threadIdx.x;
    int ch = t * 4;
    int head = t >> 5;
    float ax = 0.f, ay = 0.f, az = 0.f, aw = 0.f;
    int st = off[n], en = off[n + 1];
    for (int pos = st; pos < en; ++pos) {
        float a = alpha[(size_t)pos * 4 + head];
        uint2 vv = *(const uint2*)(vs + (size_t)srcS[pos] * 1024 + ch);
        float2 v01 = bfp2(vv.x), v23 = bfp2(vv.y);
        ax += a * v01.x; ay += a * v01.y; az += a * v23.x; aw += a * v23.y;
    }
    uint2 su = *(const uint2*)(vs + (size_t)n * 1024 + 512 + ch);
    float2 s01 = bfp2(su.x), s23 = bfp2(su.y);
    float ox = gelu1(ax + s01.x);
    float oy = gelu1(ay + s01.y);
    float oz = gelu1(az + s23.x);
    float ow = gelu1(aw + s23.y);
    const float4 hv = *(const float4*)(h + (size_t)n * 512 + ch);
    float rx = hv.x + ox, ry = hv.y + oy, rz = hv.z + oz, rw = hv.w + ow;
    float sum = rx + ry + rz + rw;
    float ssq = rx * rx + ry * ry + rz * rz + rw * rw;
    int lane = t & 63, wv = t >> 6;
    for (int o = 32; o; o >>= 1) {
        sum += __shfl_xor(sum, o);
        ssq += __shfl_xor(ssq, o);
    }
    __shared__ float red[4];
    if (lane == 0) { red[wv] = sum; red[2 + wv] = ssq; }
    __syncthreads();
    float tot = red[0] + red[1], tot2 = red[2] + red[3];
    float mean = tot * (1.0f / 512.0f);
    float var = tot2 * (1.0f / 512.0f) - mean * mean;
    float inv = rsqrtf(var + 1e-5f);
    const float4 g4 = *(const float4*)(lng + ch);
    const float4 b4 = *(const float4*)(lnb + ch);
    float4 o4;
    o4.x = (rx - mean) * inv * g4.x + b4.x;
    o4.y = (ry - mean) * inv * g4.y + b4.y;
    o4.z = (rz - mean) * inv * g4.z + b4.z;
    o4.w = (rw - mean) * inv * g4.w + b4.w;
    *(float4*)(h + (size_t)n * 512 + ch) = o4;
}

// ---------------- pair bilinear scores (bf16 z,t) ----------------

__global__ __launch_bounds__(256) void k_pairscore(const short* __restrict__ z,
                                                   const short* __restrict__ t,
                                                   const int* __restrict__ pi,
                                                   const int* __restrict__ pj,
                                                   float* __restrict__ ssyn,
                                                   float* __restrict__ sant, int P) {
    int p = blockIdx.x * 4 + (threadIdx.x >> 6);
    if (p >= P) return;
    int lane = threadIdx.x & 63;
    int i = pi[p], j = pj[p];
    uint4 a = *(const uint4*)(t + (size_t)i * 1024 + lane * 8);
    uint4 b = *(const uint4*)(z + (size_t)j * 1024 + lane * 8);
    float2 a0 = bfp2(a.x), a1 = bfp2(a.y), a2 = bfp2(a.z), a3 = bfp2(a.w);
    float2 b0 = bfp2(b.x), b1 = bfp2(b.y), b2 = bfp2(b.z), b3 = bfp2(b.w);
    float ds = a0.x * b0.x + a0.y * b0.y + a1.x * b1.x + a1.y * b1.y +
               a2.x * b2.x + a2.y * b2.y + a3.x * b3.x + a3.y * b3.y;
    uint4 c = *(const uint4*)(t + (size_t)i * 1024 + 512 + lane * 8);
    uint4 d = *(const uint4*)(z + (size_t)j * 1024 + 512 + lane * 8);
    float2 c0 = bfp2(c.x), c1 = bfp2(c.y), c2 = bfp2(c.z), c3 = bfp2(c.w);
    float2 d0 = bfp2(d.x), d1 = bfp2(d.y), d2 = bfp2(d.z), d3 = bfp2(d.w);
    float da = c0.x * d0.x + c0.y * d0.y + c1.x * d1.x + c1.y * d1.y +
               c2.x * d2.x + c2.y * d2.y + c3.x * d3.x + c3.y * d3.y;
    for (int o = 32; o; o >>= 1) {
        ds += __shfl_xor(ds, o);
        da += __shfl_xor(da, o);
    }
    if (lane == 0) { ssyn[p] = ds; sant[p] = da; }
}

// ---------------- final elementwise combine ----------------

__global__ void k_final(const float* __restrict__ gpart, const float* __restrict__ gb2,
                        const float* __restrict__ ssyn, const float* __restrict__ sant,
                        float* __restrict__ out, int P) {
    int p = blockIdx.x * 256 + threadIdx.x;
    if (p < P) {
        float s = 1.0f / (1.0f + __expf(-(gpart[p] + gb2[0])));
        out[p] = s * sant[p] - (1.0f - s) * ssyn[p];
    }
}

// ---------------- host ----------------

extern "C" void kernel_launch(void* const* d_in, const int* in_sizes, int n_in,
                              void* d_out, int out_size, void* d_ws, size_t ws_size,
                              hipStream_t stream) {
    const float* x = (const float*)d_in[0];
    const int* ei = (const int*)d_in[1];
    const int* pe = (const int*)d_in[2];
    const float* mixer_W = (const float*)d_in[3];
    const float* mixer_b = (const float*)d_in[4];
    const float* Wq = (const float*)d_in[5];
    const float* bq = (const float*)d_in[6];
    const float* Wk = (const float*)d_in[7];
    const float* bk = (const float*)d_in[8];
    const float* Wv = (const float*)d_in[9];
    const float* bv = (const float*)d_in[10];
    const float* Ws = (const float*)d_in[11];
    const float* bs = (const float*)d_in[12];
    const float* ln_g = (const float*)d_in[13];
    const float* ln_b = (const float*)d_in[14];
    const float* syn_W = (const float*)d_in[15];
    const float* syn_b = (const float*)d_in[16];
    const float* ant_W = (const float*)d_in[17];
    const float* ant_b = (const float*)d_in[18];
    const float* W_syn = (const float*)d_in[19];
    const float* W_ant = (const float*)d_in[20];
    const float* gW1 = (const float*)d_in[21];
    const float* gb1 = (const float*)d_in[22];
    const float* gW2 = (const float*)d_in[23];
    const float* gb2 = (const float*)d_in[24];
    float* out = (float*)d_out;

    const int Nn = in_sizes[0] / 768;  // 20000
    const int E = in_sizes[1] / 2;     // 320000
    const int P = in_sizes[2] / 2;     // 100000

    char* w = (char*)d_ws;
    auto alloc = [&](size_t bytes) -> char* {
        char* p = w;
        w += (bytes + 255) & ~(size_t)255;
        return p;
    };
    float* h = (float*)alloc((size_t)Nn * 512 * 4);           // 41 MB
    short* B1 = (short*)alloc((size_t)Nn * 1024 * 2);         // 41 MB: qk / vs, later z
    short* B2 = (short*)alloc((size_t)Nn * 1024 * 2);         // 41 MB: t
    float* logits = (float*)alloc((size_t)E * 4 * 4);         // 5.1 MB; alpha in-place
    int* srcS = (int*)alloc((size_t)E * 4);
    int* dstS = (int*)alloc((size_t)E * 4);
    int* hist = (int*)alloc((size_t)Nn * 2 * 4);
    int* cursor = hist + Nn;
    int* offs = (int*)alloc((size_t)(Nn + 1) * 4);
    short* mixWt = (short*)alloc((size_t)512 * 768 * 2);
    short* wcat = (short*)alloc((size_t)L_LAYERS * 2048 * 512 * 2);
    short* dualWt = (short*)alloc((size_t)1024 * 512 * 2);
    short* bilWt = (short*)alloc((size_t)1024 * 512 * 2);
    short* gw1t = (short*)alloc((size_t)512 * 2048 * 2);
    float* bcat = (float*)alloc((size_t)L_LAYERS * 2048 * 4);
    float* bdual = (float*)alloc((size_t)1024 * 4);
    // phase-3 overlays onto dead logits region
    float* ssyn = logits;
    float* sant = logits + P;
    float* gpart = logits + 2 * P;

    k_zero<<<(2 * Nn + 255) / 256, 256, 0, stream>>>(hist, 2 * Nn);
    k_hist<<<(E + 255) / 256, 256, 0, stream>>>(ei + E, hist, E);
    k_scan<<<1, 1024, 0, stream>>>(hist, offs, Nn);
    k_scatter<<<(E + 255) / 256, 256, 0, stream>>>(ei, ei + E, offs, cursor, srcS, dstS, E);

    k_wcat<<<(L_LAYERS * 2048 * 512) / 256, 256, 0, stream>>>(Wq, Wk, Wv, Ws, wcat);
    k_tr<<<dim3(3, 512), 256, 0, stream>>>(mixer_W, mixWt, 768, 512);
    k_tr<<<dim3(2, 512), 256, 0, stream>>>(syn_W, dualWt, 512, 512);
    k_tr<<<dim3(2, 512), 256, 0, stream>>>(ant_W, dualWt + 512 * 512, 512, 512);
    k_tr<<<dim3(2, 512), 256, 0, stream>>>(W_syn, bilWt, 512, 512);
    k_tr<<<dim3(2, 512), 256, 0, stream>>>(W_ant, bilWt + 512 * 512, 512, 512);
    k_tr<<<dim3(8, 512), 256, 0, stream>>>(gW1, gw1t, 2048, 512);
    k_bcat<<<48, 256, 0, stream>>>(bq, bk, bv, bs, bcat);
    k_bdual<<<4, 256, 0, stream>>>(syn_b, ant_b, bdual);

    const int mtiles = (Nn + 127) / 128;  // 157
    // mixer: h = gelu(x @ mixer_W + b), fp32 out
    gemm_a32<<<dim3(mtiles, 4), 256, 0, stream>>>(x, 768, mixWt, mixer_b, h, 512,
                                                  Nn, 512, 768, 1, 0);

    for (int l = 0; l < L_LAYERS; ++l) {
        const short* wl = wcat + (size_t)l * 2048 * 512;
        const float* bl = bcat + l * 2048;
        // q|k -> B1 bf16
        gemm_a32<<<dim3(mtiles, 8), 256, 0, stream>>>(h, 512, wl, bl, B1, 1024,
                                                      Nn, 1024, 512, 0, 1);
        k_logits<<<(E + 3) / 4, 256, 0, stream>>>(B1, srcS, dstS, logits, E);
        k_softmax<<<(Nn + 3) / 4, 256, 0, stream>>>(logits, offs, Nn);
        // v|s -> B1 bf16 (overwrites qk)
        gemm_a32<<<dim3(mtiles, 8), 256, 0, stream>>>(h, 512, wl + (size_t)1024 * 512,
                                                      bl + 1024, B1, 1024, Nn, 1024, 512, 0, 1);
        k_aggregate<<<Nn, 128, 0, stream>>>(B1, srcS, offs, logits, h,
                                            ln_g + l * 512, ln_b + l * 512, Nn);
    }

    // z = gelu(h @ [syn_W|ant_W] + b) -> B1 bf16 [Nn][1024]
    gemm_a32<<<dim3(mtiles, 8), 256, 0, stream>>>(h, 512, dualWt, bdual, B1, 1024,
                                                  Nn, 1024, 512, 1, 1);
    // t = z @ W -> B2 bf16 [Nn][1024]
    gemm_abf<<<dim3(mtiles, 4), 256, 0, stream>>>(B1, 1024, bilWt, B2, 1024, Nn, 512, 512);
    gemm_abf<<<dim3(mtiles, 4), 256, 0, stream>>>(B1 + 512, 1024, bilWt + 512 * 512,
                                                  B2 + 512, 1024, Nn, 512, 512);

    k_pairscore<<<(P + 3) / 4, 256, 0, stream>>>(B1, B2, pe, pe + P, ssyn, sant, P);

    // fused gate MLP (pairing trick) + final combine
    k_zero<<<(P + 255) / 256, 256, 0, stream>>>((int*)gpart, P);
    gemm_gate<<<dim3((P + 63) / 64, 2), 256, 0, stream>>>(B1, pe, pe + P, P,
                                                          gw1t, gb1, gW2, gpart);
    k_final<<<(P + 255) / 256, 256, 0, stream>>>(gpart, gb2, ssyn, sant, out, P);
}

// Round 5
// 2263.136 us; speedup vs baseline: 1.2976x; 1.1115x over previous
//
#include <hip/hip_runtime.h>
#include <cstdint>

#define L_LAYERS 6

typedef __attribute__((ext_vector_type(8))) short bf16x8;
typedef __attribute__((ext_vector_type(4))) float f32x4;

__device__ __forceinline__ float gelu1(float v) {
    return 0.5f * v * (1.0f + erff(v * 0.7071067811865475f));
}

__device__ __forceinline__ unsigned int f2bf2(float a, float b) {
    union { float f; unsigned u; } x, y;
    x.f = a; y.f = b;
    unsigned lo = (x.u + 0x7FFFu + ((x.u >> 16) & 1u)) >> 16;
    unsigned hi = (y.u + 0x7FFFu + ((y.u >> 16) & 1u)) & 0xFFFF0000u;
    return lo | hi;
}

__device__ __forceinline__ unsigned short f2bf1(float a) {
    union { float f; unsigned u; } x;
    x.f = a;
    return (unsigned short)((x.u + 0x7FFFu + ((x.u >> 16) & 1u)) >> 16);
}

__device__ __forceinline__ float2 bfp2(unsigned u) {
    union { unsigned u; float f; } a, b;
    a.u = u << 16;
    b.u = u & 0xFFFF0000u;
    return make_float2(a.f, b.f);
}

// async global->LDS, 16 bytes per lane
__device__ __forceinline__ void gload16(const void* g, void* l) {
    __builtin_amdgcn_global_load_lds(
        (const __attribute__((address_space(1))) void*)g,
        (__attribute__((address_space(3))) void*)l, 16, 0, 0);
}

// ---------------- utility ----------------

__global__ void k_zero(int* __restrict__ p, int n) {
    int i = blockIdx.x * 256 + threadIdx.x;
    if (i < n) p[i] = 0;
}

// ---------------- edge sorting (counting sort by dst) ----------------

__global__ void k_hist(const int* __restrict__ dst, int* __restrict__ hist, int E) {
    int e = blockIdx.x * 256 + threadIdx.x;
    if (e < E) atomicAdd(&hist[dst[e]], 1);
}

__global__ __launch_bounds__(1024) void k_scan(const int* __restrict__ hist,
                                               int* __restrict__ off, int n) {
    __shared__ int buf[1024];
    __shared__ int carry;
    int tid = threadIdx.x;
    if (tid == 0) carry = 0;
    __syncthreads();
    for (int base = 0; base < n; base += 1024) {
        int v = (base + tid < n) ? hist[base + tid] : 0;
        buf[tid] = v;
        __syncthreads();
        int x = v;
        for (int o = 1; o < 1024; o <<= 1) {
            int t = (tid >= o) ? buf[tid - o] : 0;
            __syncthreads();
            x += t;
            buf[tid] = x;
            __syncthreads();
        }
        int c = carry;
        if (base + tid < n) off[base + tid] = c + x - v;   // exclusive
        __syncthreads();
        if (tid == 1023) carry = c + buf[1023];
        __syncthreads();
    }
    if (tid == 0) off[n] = carry;
}

__global__ void k_scatter(const int* __restrict__ src, const int* __restrict__ dst,
                          const int* __restrict__ off, int* __restrict__ cursor,
                          int* __restrict__ srcS, int E) {
    int e = blockIdx.x * 256 + threadIdx.x;
    if (e < E) {
        int d = dst[e];
        int pos = off[d] + atomicAdd(&cursor[d], 1);
        srcS[pos] = src[e];
    }
}

// ---------------- weight prep (transpose + cvt to bf16) ----------------

__global__ void k_wcat(const float* __restrict__ Wq, const float* __restrict__ Wk,
                       const float* __restrict__ Wv, const float* __restrict__ Ws,
                       short* __restrict__ Wt) {
    int idx = blockIdx.x * 256 + threadIdx.x;   // l*2^20 + n*512 + k
    int k = idx & 511;
    int nf = (idx >> 9) & 2047;
    int l = idx >> 20;
    int sel = nf >> 9, nn = nf & 511;
    const float* W = (sel == 0) ? Wq : (sel == 1) ? Wk : (sel == 2) ? Wv : Ws;
    float v = W[((size_t)l * 512 + k) * 512 + nn];
    Wt[idx] = (short)f2bf1(v);
}

__global__ void k_tr(const float* __restrict__ W, short* __restrict__ Wt, int K, int N) {
    int k = blockIdx.x * 256 + threadIdx.x;
    int n = blockIdx.y;
    if (k < K) Wt[(size_t)n * K + k] = (short)f2bf1(W[(size_t)k * N + n]);
}

__global__ void k_bcat(const float* __restrict__ bq, const float* __restrict__ bk,
                       const float* __restrict__ bv, const float* __restrict__ bs,
                       float* __restrict__ bcat) {
    int idx = blockIdx.x * 256 + threadIdx.x;
    if (idx >= L_LAYERS * 2048) return;
    int l = idx >> 11, n = idx & 2047;
    int sel = n >> 9, nn = n & 511;
    const float* b = (sel == 0) ? bq : (sel == 1) ? bk : (sel == 2) ? bv : bs;
    bcat[idx] = b[l * 512 + nn];
}

__global__ void k_bdual(const float* __restrict__ sb, const float* __restrict__ ab,
                        float* __restrict__ bd) {
    int idx = blockIdx.x * 256 + threadIdx.x;
    if (idx < 1024) bd[idx] = (idx < 512) ? sb[idx] : ab[idx - 512];
}

// ---------------- GEMM: A fp32 (mixer only) ----------------
// C = act(A*Bt^T + bias); fp32 out + optional bf16 copy.

__global__ __launch_bounds__(256) void gemm_a32(
    const float* __restrict__ A, int lda,
    const short* __restrict__ Bt,
    const float* __restrict__ bias,
    float* __restrict__ Cf, short* __restrict__ Cbf, int ldc,
    int M, int N, int K, int act) {
    __shared__ __align__(16) short As[128][40];
    __shared__ __align__(16) short Bs[128][40];
    const int tid = threadIdx.x;
    const int lane = tid & 63;
    const int wave = tid >> 6;
    const int wr = (wave >> 1) * 64;
    const int wc = (wave & 1) * 64;
    const int l16 = lane & 15;
    const int quad = lane >> 4;
    const int row0 = blockIdx.x * 128;
    const int col0 = blockIdx.y * 128;
    const int sr = tid >> 2;
    const int sk = (tid & 3) * 8;

    f32x4 acc[4][4];
#pragma unroll
    for (int i = 0; i < 4; ++i)
#pragma unroll
        for (int j = 0; j < 4; ++j)
            acc[i][j] = f32x4{0.f, 0.f, 0.f, 0.f};

    for (int kb = 0; kb < K; kb += 32) {
#pragma unroll
        for (int hh = 0; hh < 2; ++hh) {
            int r = sr + hh * 64;
            int gr = row0 + r;
            float4 a0, a1;
            if (gr < M) {
                const float* p = A + (size_t)gr * lda + kb + sk;
                a0 = *(const float4*)p;
                a1 = *(const float4*)(p + 4);
            } else {
                a0 = make_float4(0.f, 0.f, 0.f, 0.f);
                a1 = make_float4(0.f, 0.f, 0.f, 0.f);
            }
            uint4 av;
            av.x = f2bf2(a0.x, a0.y);
            av.y = f2bf2(a0.z, a0.w);
            av.z = f2bf2(a1.x, a1.y);
            av.w = f2bf2(a1.z, a1.w);
            *(uint4*)&As[r][sk] = av;
            const short* bp = Bt + (size_t)(col0 + r) * K + kb + sk;
            *(uint4*)&Bs[r][sk] = *(const uint4*)bp;
        }
        __syncthreads();
        bf16x8 af[4], bfr[4];
#pragma unroll
        for (int i = 0; i < 4; ++i)
            af[i] = *(const bf16x8*)&As[wr + i * 16 + l16][quad * 8];
#pragma unroll
        for (int j = 0; j < 4; ++j)
            bfr[j] = *(const bf16x8*)&Bs[wc + j * 16 + l16][quad * 8];
#pragma unroll
        for (int i = 0; i < 4; ++i)
#pragma unroll
            for (int j = 0; j < 4; ++j)
                acc[i][j] = __builtin_amdgcn_mfma_f32_16x16x32_bf16(af[i], bfr[j], acc[i][j], 0, 0, 0);
        __syncthreads();
    }
#pragma unroll
    for (int i = 0; i < 4; ++i) {
        int rbase = row0 + wr + i * 16 + quad * 4;
#pragma unroll
        for (int j = 0; j < 4; ++j) {
            int c = col0 + wc + j * 16 + l16;
            float bv = bias ? bias[c] : 0.0f;
#pragma unroll
            for (int rg = 0; rg < 4; ++rg) {
                int gr = rbase + rg;
                if (gr < M) {
                    float v = acc[i][j][rg] + bv;
                    if (act) v = gelu1(v);
                    Cf[(size_t)gr * ldc + c] = v;
                    if (Cbf) Cbf[(size_t)gr * ldc + c] = (short)f2bf1(v);
                }
            }
        }
    }
}

// ---------------- GEMM: A bf16, B bf16, m97-style global_load_lds staging ----------------
// C bf16 = act(A*Bt^T + bias). 128x128 tile, BK=32, LDS unpadded (contiguous chunk order).

__global__ __launch_bounds__(256) void gemm_bb(
    const short* __restrict__ A, int lda,
    const short* __restrict__ Bt,
    const float* __restrict__ bias,
    short* __restrict__ C, int ldc,
    int M, int N, int K, int act) {
    __shared__ __align__(16) short As[128 * 32];
    __shared__ __align__(16) short Bs[128 * 32];
    const int tid = threadIdx.x;
    const int lane = tid & 63;
    const int wave = tid >> 6;
    const int wr = (wave >> 1) * 64;
    const int wc = (wave & 1) * 64;
    const int l16 = lane & 15;
    const int quad = lane >> 4;
    const int row0 = blockIdx.x * 128;
    const int col0 = blockIdx.y * 128;
    // chunk c (0..511): r = c>>2, kq = (c&3)*8 ; lds offset c*8 shorts
    const int c0 = tid, c1 = tid + 256;
    const int r0 = c0 >> 2, kq0 = (c0 & 3) * 8;
    const int r1 = c1 >> 2, kq1 = (c1 & 3) * 8;
    int ga0 = row0 + r0; if (ga0 >= M) ga0 = M - 1;
    int ga1 = row0 + r1; if (ga1 >= M) ga1 = M - 1;
    const short* Ap0 = A + (size_t)ga0 * lda + kq0;
    const short* Ap1 = A + (size_t)ga1 * lda + kq1;
    const short* Bp0 = Bt + (size_t)(col0 + r0) * K + kq0;
    const short* Bp1 = Bt + (size_t)(col0 + r1) * K + kq1;

    f32x4 acc[4][4];
#pragma unroll
    for (int i = 0; i < 4; ++i)
#pragma unroll
        for (int j = 0; j < 4; ++j)
            acc[i][j] = f32x4{0.f, 0.f, 0.f, 0.f};

    for (int kb = 0; kb < K; kb += 32) {
        gload16(Ap0 + kb, &As[c0 * 8]);
        gload16(Ap1 + kb, &As[c1 * 8]);
        gload16(Bp0 + kb, &Bs[c0 * 8]);
        gload16(Bp1 + kb, &Bs[c1 * 8]);
        __syncthreads();
        bf16x8 af[4], bfr[4];
#pragma unroll
        for (int i = 0; i < 4; ++i)
            af[i] = *(const bf16x8*)&As[(wr + i * 16 + l16) * 32 + quad * 8];
#pragma unroll
        for (int j = 0; j < 4; ++j)
            bfr[j] = *(const bf16x8*)&Bs[(wc + j * 16 + l16) * 32 + quad * 8];
#pragma unroll
        for (int i = 0; i < 4; ++i)
#pragma unroll
            for (int j = 0; j < 4; ++j)
                acc[i][j] = __builtin_amdgcn_mfma_f32_16x16x32_bf16(af[i], bfr[j], acc[i][j], 0, 0, 0);
        __syncthreads();
    }
#pragma unroll
    for (int i = 0; i < 4; ++i) {
        int rbase = row0 + wr + i * 16 + quad * 4;
#pragma unroll
        for (int j = 0; j < 4; ++j) {
            int c = col0 + wc + j * 16 + l16;
            float bv = bias ? bias[c] : 0.0f;
#pragma unroll
            for (int rg = 0; rg < 4; ++rg) {
                int gr = rbase + rg;
                if (gr < M) {
                    float v = acc[i][j][rg] + bv;
                    if (act) v = gelu1(v);
                    C[(size_t)gr * ldc + c] = (short)f2bf1(v);
                }
            }
        }
    }
}

// ---------------- fused gate GEMM (pairing trick, unchanged from R4) ----------------

__global__ __launch_bounds__(256, 3) void gemm_gate(
    const short* __restrict__ z,
    const int* __restrict__ pi, const int* __restrict__ pj, int P,
    const short* __restrict__ Bt,    // gW1^T [512][2048]
    const float* __restrict__ gb1,
    const float* __restrict__ gW2,
    float* __restrict__ gpart) {
    __shared__ __align__(16) short Aab[64][40];
    __shared__ __align__(16) short Amu[64][40];
    __shared__ __align__(16) short Bab[256][40];
    __shared__ __align__(16) short Bmu[256][40];
    __shared__ int iArr[64];
    __shared__ int jArr[64];
    __shared__ float rowsum[64];
    const int tid = threadIdx.x;
    const int lane = tid & 63;
    const int wave = tid >> 6;
    const int wc = wave * 64;
    const int l16 = lane & 15;
    const int quad = lane >> 4;
    const int row0 = blockIdx.x * 64;
    const int col0 = blockIdx.y * 256;
    const int sr = tid >> 2;
    const int sk = (tid & 3) * 8;

    if (tid < 64) {
        int p = row0 + tid;
        int ok = (p < P);
        iArr[tid] = ok ? pi[p] : 0;
        jArr[tid] = ok ? pj[p] : 0;
        rowsum[tid] = 0.0f;
    }
    __syncthreads();
    const short* zi = z + (size_t)iArr[sr] * 1024 + sk;
    const short* zj = z + (size_t)jArr[sr] * 1024 + sk;
    const short* bp0 = Bt + (size_t)(col0 + sr) * 2048 + sk;

    f32x4 acc[4][4];
#pragma unroll
    for (int i = 0; i < 4; ++i)
#pragma unroll
        for (int j = 0; j < 4; ++j)
            acc[i][j] = f32x4{0.f, 0.f, 0.f, 0.f};

    for (int part = 0; part < 2; ++part) {
        for (int c = 0; c < 512; c += 32) {
            uint4 xu = *(const uint4*)(zi + part * 512 + c);
            uint4 yu = *(const uint4*)(zj + part * 512 + c);
            float2 x0 = bfp2(xu.x), x1 = bfp2(xu.y), x2 = bfp2(xu.z), x3 = bfp2(xu.w);
            float2 y0 = bfp2(yu.x), y1 = bfp2(yu.y), y2 = bfp2(yu.z), y3 = bfp2(yu.w);
            uint4 aa, am;
            aa.x = f2bf2(fabsf(x0.x - y0.x), fabsf(x0.y - y0.y));
            aa.y = f2bf2(fabsf(x1.x - y1.x), fabsf(x1.y - y1.y));
            aa.z = f2bf2(fabsf(x2.x - y2.x), fabsf(x2.y - y2.y));
            aa.w = f2bf2(fabsf(x3.x - y3.x), fabsf(x3.y - y3.y));
            am.x = f2bf2(x0.x * y0.x, x0.y * y0.y);
            am.y = f2bf2(x1.x * y1.x, x1.y * y1.y);
            am.z = f2bf2(x2.x * y2.x, x2.y * y2.y);
            am.w = f2bf2(x3.x * y3.x, x3.y * y3.y);
            *(uint4*)&Aab[sr][sk] = aa;
            *(uint4*)&Amu[sr][sk] = am;
            const short* bp = bp0 + part * 1024 + c;
#pragma unroll
            for (int hh = 0; hh < 4; ++hh) {
                const short* q = bp + (size_t)hh * 64 * 2048;
                *(uint4*)&Bab[sr + hh * 64][sk] = *(const uint4*)q;
                *(uint4*)&Bmu[sr + hh * 64][sk] = *(const uint4*)(q + 512);
            }
            __syncthreads();
            bf16x8 af[4];
#pragma unroll
            for (int i = 0; i < 4; ++i)
                af[i] = *(const bf16x8*)&Aab[i * 16 + l16][quad * 8];
#pragma unroll
            for (int j = 0; j < 4; ++j) {
                bf16x8 bf = *(const bf16x8*)&Bab[wc + j * 16 + l16][quad * 8];
#pragma unroll
                for (int i = 0; i < 4; ++i)
                    acc[i][j] = __builtin_amdgcn_mfma_f32_16x16x32_bf16(af[i], bf, acc[i][j], 0, 0, 0);
            }
#pragma unroll
            for (int i = 0; i < 4; ++i)
                af[i] = *(const bf16x8*)&Amu[i * 16 + l16][quad * 8];
#pragma unroll
            for (int j = 0; j < 4; ++j) {
                bf16x8 bf = *(const bf16x8*)&Bmu[wc + j * 16 + l16][quad * 8];
#pragma unroll
                for (int i = 0; i < 4; ++i)
                    acc[i][j] = __builtin_amdgcn_mfma_f32_16x16x32_bf16(af[i], bf, acc[i][j], 0, 0, 0);
            }
            __syncthreads();
        }
    }
#pragma unroll
    for (int i = 0; i < 4; ++i) {
#pragma unroll
        for (int rg = 0; rg < 4; ++rg) {
            float partial = 0.f;
#pragma unroll
            for (int j = 0; j < 4; ++j) {
                int cc = col0 + wc + j * 16 + l16;
                partial += gelu1(acc[i][j][rg] + gb1[cc]) * gW2[cc];
            }
            partial += __shfl_xor(partial, 1);
            partial += __shfl_xor(partial, 2);
            partial += __shfl_xor(partial, 4);
            partial += __shfl_xor(partial, 8);
            if (l16 == 0)
                atomicAdd(&rowsum[i * 16 + quad * 4 + rg], partial);
        }
    }
    __syncthreads();
    if (tid < 64 && (row0 + tid) < P)
        atomicAdd(&gpart[row0 + tid], rowsum[tid]);
}

// ---------------- fused per-layer attention (flash-style segment softmax) ----------------
// qkvs bf16 [Nn][2048]: q|k|v|s at +0/+512/+1024/+1536. One block (256 thr) per node.
// Online softmax over incoming-edge chunks of 128; aggregate v; +s, gelu, residual, LN.

__global__ __launch_bounds__(256) void k_attn(const short* __restrict__ qkvs,
                                              const int* __restrict__ srcS,
                                              const int* __restrict__ offs,
                                              float* __restrict__ h,
                                              short* __restrict__ h_bf,
                                              const float* __restrict__ lng,
                                              const float* __restrict__ lnb) {
    __shared__ float Llog[128][4];
    __shared__ float m_s[4], l_s[4], sc_s[4];
    __shared__ float comb[128][4];
    __shared__ float red[4], red2[4];
    const int n = blockIdx.x;
    const int tid = threadIdx.x;
    const int lane = tid & 63;
    const int wave = tid >> 6;
    const int half = tid >> 7;
    const int t2 = tid & 127;
    const int ch = t2 * 4;
    const int headA = t2 >> 5;
    const int hq = lane >> 4, li = lane & 15;
    const int st = offs[n], en = offs[n + 1];

    if (tid < 4) { m_s[tid] = -3.4e38f; l_s[tid] = 0.f; sc_s[tid] = 1.f; }
    // own q fragment (per-lane 8 bf16 of head hq)
    uint4 qv = *(const uint4*)(qkvs + (size_t)n * 2048 + hq * 128 + li * 8);
    float2 q0 = bfp2(qv.x), q1 = bfp2(qv.y), q2 = bfp2(qv.z), q3 = bfp2(qv.w);
    float ax = 0.f, ay = 0.f, az = 0.f, aw = 0.f;
    __syncthreads();

    for (int e0 = st; e0 < en; e0 += 128) {
        int cnt = min(128, en - e0);
        // --- logits: wave handles edges e0+wave, stride 4 ---
        for (int ei = wave; ei < cnt; ei += 4) {
            int s = srcS[e0 + ei];
            uint4 kv = *(const uint4*)(qkvs + (size_t)s * 2048 + 512 + hq * 128 + li * 8);
            float2 k0 = bfp2(kv.x), k1 = bfp2(kv.y), k2 = bfp2(kv.z), k3 = bfp2(kv.w);
            float dot = q0.x * k0.x + q0.y * k0.y + q1.x * k1.x + q1.y * k1.y +
                        q2.x * k2.x + q2.y * k2.y + q3.x * k3.x + q3.y * k3.y;
            dot += __shfl_xor(dot, 1);
            dot += __shfl_xor(dot, 2);
            dot += __shfl_xor(dot, 4);
            dot += __shfl_xor(dot, 8);
            if (li == 0) Llog[ei][hq] = dot * 0.08838834764831845f;
        }
        __syncthreads();
        // --- per-head online-softmax update: wave w handles head w ---
        {
            float m_old = m_s[wave];
            float mc = -3.4e38f;
            for (int i = lane; i < cnt; i += 64) mc = fmaxf(mc, Llog[i][wave]);
            for (int o = 32; o; o >>= 1) mc = fmaxf(mc, __shfl_xor(mc, o));
            float m_new = fmaxf(m_old, mc);
            float sum = 0.f;
            for (int i = lane; i < cnt; i += 64) {
                float p = __expf(Llog[i][wave] - m_new);
                Llog[i][wave] = p;
                sum += p;
            }
            for (int o = 32; o; o >>= 1) sum += __shfl_xor(sum, o);
            if (lane == 0) {
                float sc = __expf(m_old - m_new);
                sc_s[wave] = sc;
                l_s[wave] = l_s[wave] * sc + sum;
                m_s[wave] = m_new;
            }
        }
        __syncthreads();
        // --- aggregate: half-block per alternating edge ---
        float sc = sc_s[headA];
        ax *= sc; ay *= sc; az *= sc; aw *= sc;
        for (int ei = half; ei < cnt; ei += 2) {
            float a = Llog[ei][headA];
            int s = srcS[e0 + ei];
            uint2 vv = *(const uint2*)(qkvs + (size_t)s * 2048 + 1024 + ch);
            float2 v01 = bfp2(vv.x), v23 = bfp2(vv.y);
            ax += a * v01.x; ay += a * v01.y; az += a * v23.x; aw += a * v23.y;
        }
        __syncthreads();
    }
    // combine halves
    if (half == 1) { comb[t2][0] = ax; comb[t2][1] = ay; comb[t2][2] = az; comb[t2][3] = aw; }
    __syncthreads();
    float rx = 0.f, ry = 0.f, rz = 0.f, rw = 0.f, sum = 0.f, ssq = 0.f;
    if (half == 0) {
        ax += comb[t2][0]; ay += comb[t2][1]; az += comb[t2][2]; aw += comb[t2][3];
        float rinv = (en > st) ? 1.0f / l_s[headA] : 0.0f;
        ax *= rinv; ay *= rinv; az *= rinv; aw *= rinv;
        uint2 su = *(const uint2*)(qkvs + (size_t)n * 2048 + 1536 + ch);
        float2 s01 = bfp2(su.x), s23 = bfp2(su.y);
        const float4 hv = *(const float4*)(h + (size_t)n * 512 + ch);
        rx = hv.x + gelu1(ax + s01.x);
        ry = hv.y + gelu1(ay + s01.y);
        rz = hv.z + gelu1(az + s23.x);
        rw = hv.w + gelu1(aw + s23.y);
        sum = rx + ry + rz + rw;
        ssq = rx * rx + ry * ry + rz * rz + rw * rw;
    }
    for (int o = 32; o; o >>= 1) {
        sum += __shfl_xor(sum, o);
        ssq += __shfl_xor(ssq, o);
    }
    if (lane == 0) { red[wave] = sum; red2[wave] = ssq; }
    __syncthreads();
    if (half == 0) {
        float tot = red[0] + red[1];
        float tot2 = red2[0] + red2[1];
        float mean = tot * (1.0f / 512.0f);
        float var = tot2 * (1.0f / 512.0f) - mean * mean;
        float inv = rsqrtf(var + 1e-5f);
        const float4 g4 = *(const float4*)(lng + ch);
        const float4 b4 = *(const float4*)(lnb + ch);
        float4 o4;
        o4.x = (rx - mean) * inv * g4.x + b4.x;
        o4.y = (ry - mean) * inv * g4.y + b4.y;
        o4.z = (rz - mean) * inv * g4.z + b4.z;
        o4.w = (rw - mean) * inv * g4.w + b4.w;
        *(float4*)(h + (size_t)n * 512 + ch) = o4;
        uint2 ob;
        ob.x = f2bf2(o4.x, o4.y);
        ob.y = f2bf2(o4.z, o4.w);
        *(uint2*)(h_bf + (size_t)n * 512 + ch) = ob;
    }
}

// ---------------- pair bilinear scores (bf16 z,t) ----------------

__global__ __launch_bounds__(256) void k_pairscore(const short* __restrict__ z,
                                                   const short* __restrict__ t,
                                                   const int* __restrict__ pi,
                                                   const int* __restrict__ pj,
                                                   float* __restrict__ ssyn,
                                                   float* __restrict__ sant, int P) {
    int p = blockIdx.x * 4 + (threadIdx.x >> 6);
    if (p >= P) return;
    int lane = threadIdx.x & 63;
    int i = pi[p], j = pj[p];
    uint4 a = *(const uint4*)(t + (size_t)i * 1024 + lane * 8);
    uint4 b = *(const uint4*)(z + (size_t)j * 1024 + lane * 8);
    float2 a0 = bfp2(a.x), a1 = bfp2(a.y), a2 = bfp2(a.z), a3 = bfp2(a.w);
    float2 b0 = bfp2(b.x), b1 = bfp2(b.y), b2 = bfp2(b.z), b3 = bfp2(b.w);
    float ds = a0.x * b0.x + a0.y * b0.y + a1.x * b1.x + a1.y * b1.y +
               a2.x * b2.x + a2.y * b2.y + a3.x * b3.x + a3.y * b3.y;
    uint4 c = *(const uint4*)(t + (size_t)i * 1024 + 512 + lane * 8);
    uint4 d = *(const uint4*)(z + (size_t)j * 1024 + 512 + lane * 8);
    float2 c0 = bfp2(c.x), c1 = bfp2(c.y), c2 = bfp2(c.z), c3 = bfp2(c.w);
    float2 d0 = bfp2(d.x), d1 = bfp2(d.y), d2 = bfp2(d.z), d3 = bfp2(d.w);
    float da = c0.x * d0.x + c0.y * d0.y + c1.x * d1.x + c1.y * d1.y +
               c2.x * d2.x + c2.y * d2.y + c3.x * d3.x + c3.y * d3.y;
    for (int o = 32; o; o >>= 1) {
        ds += __shfl_xor(ds, o);
        da += __shfl_xor(da, o);
    }
    if (lane == 0) { ssyn[p] = ds; sant[p] = da; }
}

// ---------------- final elementwise combine ----------------

__global__ void k_final(const float* __restrict__ gpart, const float* __restrict__ gb2,
                        const float* __restrict__ ssyn, const float* __restrict__ sant,
                        float* __restrict__ out, int P) {
    int p = blockIdx.x * 256 + threadIdx.x;
    if (p < P) {
        float s = 1.0f / (1.0f + __expf(-(gpart[p] + gb2[0])));
        out[p] = s * sant[p] - (1.0f - s) * ssyn[p];
    }
}

// ---------------- host ----------------

extern "C" void kernel_launch(void* const* d_in, const int* in_sizes, int n_in,
                              void* d_out, int out_size, void* d_ws, size_t ws_size,
                              hipStream_t stream) {
    const float* x = (const float*)d_in[0];
    const int* ei = (const int*)d_in[1];
    const int* pe = (const int*)d_in[2];
    const float* mixer_W = (const float*)d_in[3];
    const float* mixer_b = (const float*)d_in[4];
    const float* Wq = (const float*)d_in[5];
    const float* bq = (const float*)d_in[6];
    const float* Wk = (const float*)d_in[7];
    const float* bk = (const float*)d_in[8];
    const float* Wv = (const float*)d_in[9];
    const float* bv = (const float*)d_in[10];
    const float* Ws = (const float*)d_in[11];
    const float* bs = (const float*)d_in[12];
    const float* ln_g = (const float*)d_in[13];
    const float* ln_b = (const float*)d_in[14];
    const float* syn_W = (const float*)d_in[15];
    const float* syn_b = (const float*)d_in[16];
    const float* ant_W = (const float*)d_in[17];
    const float* ant_b = (const float*)d_in[18];
    const float* W_syn = (const float*)d_in[19];
    const float* W_ant = (const float*)d_in[20];
    const float* gW1 = (const float*)d_in[21];
    const float* gb1 = (const float*)d_in[22];
    const float* gW2 = (const float*)d_in[23];
    const float* gb2 = (const float*)d_in[24];
    float* out = (float*)d_out;

    const int Nn = in_sizes[0] / 768;  // 20000
    const int E = in_sizes[1] / 2;     // 320000
    const int P = in_sizes[2] / 2;     // 100000

    char* w = (char*)d_ws;
    auto alloc = [&](size_t bytes) -> char* {
        char* p = w;
        w += (bytes + 255) & ~(size_t)255;
        return p;
    };
    float* h = (float*)alloc((size_t)Nn * 512 * 4);        // 41 MB fp32 residual stream
    short* h_bf = (short*)alloc((size_t)Nn * 512 * 2);     // 20.5 MB bf16 GEMM input
    short* qkvs = (short*)alloc((size_t)Nn * 2048 * 2);    // 82 MB; later z (first half) | t (second)
    short* zB = qkvs;                                      // [Nn][1024] after layers
    short* tB = qkvs + (size_t)Nn * 1024;                  // [Nn][1024]
    float* ssyn = (float*)alloc((size_t)P * 3 * 4);        // ssyn|sant|gpart
    float* sant = ssyn + P;
    float* gpart = ssyn + 2 * P;
    int* srcS = (int*)alloc((size_t)E * 4);
    int* hist = (int*)alloc((size_t)Nn * 2 * 4);
    int* cursor = hist + Nn;
    int* offs = (int*)alloc((size_t)(Nn + 1) * 4);
    short* mixWt = (short*)alloc((size_t)512 * 768 * 2);
    short* wcat = (short*)alloc((size_t)L_LAYERS * 2048 * 512 * 2);
    short* dualWt = (short*)alloc((size_t)1024 * 512 * 2);
    short* bilWt = (short*)alloc((size_t)1024 * 512 * 2);
    short* gw1t = (short*)alloc((size_t)512 * 2048 * 2);
    float* bcat = (float*)alloc((size_t)L_LAYERS * 2048 * 4);
    float* bdual = (float*)alloc((size_t)1024 * 4);

    k_zero<<<(2 * Nn + 255) / 256, 256, 0, stream>>>(hist, 2 * Nn);
    k_hist<<<(E + 255) / 256, 256, 0, stream>>>(ei + E, hist, E);
    k_scan<<<1, 1024, 0, stream>>>(hist, offs, Nn);
    k_scatter<<<(E + 255) / 256, 256, 0, stream>>>(ei, ei + E, offs, cursor, srcS, E);

    k_wcat<<<(L_LAYERS * 2048 * 512) / 256, 256, 0, stream>>>(Wq, Wk, Wv, Ws, wcat);
    k_tr<<<dim3(3, 512), 256, 0, stream>>>(mixer_W, mixWt, 768, 512);
    k_tr<<<dim3(2, 512), 256, 0, stream>>>(syn_W, dualWt, 512, 512);
    k_tr<<<dim3(2, 512), 256, 0, stream>>>(ant_W, dualWt + 512 * 512, 512, 512);
    k_tr<<<dim3(2, 512), 256, 0, stream>>>(W_syn, bilWt, 512, 512);
    k_tr<<<dim3(2, 512), 256, 0, stream>>>(W_ant, bilWt + 512 * 512, 512, 512);
    k_tr<<<dim3(8, 512), 256, 0, stream>>>(gW1, gw1t, 2048, 512);
    k_bcat<<<48, 256, 0, stream>>>(bq, bk, bv, bs, bcat);
    k_bdual<<<4, 256, 0, stream>>>(syn_b, ant_b, bdual);

    const int mtiles = (Nn + 127) / 128;  // 157
    // mixer: h = gelu(x @ mixer_W + b), fp32 + bf16 copy
    gemm_a32<<<dim3(mtiles, 4), 256, 0, stream>>>(x, 768, mixWt, mixer_b, h, h_bf, 512,
                                                  Nn, 512, 768, 1);

    for (int l = 0; l < L_LAYERS; ++l) {
        // q|k|v|s -> qkvs bf16 [Nn][2048]
        gemm_bb<<<dim3(mtiles, 16), 256, 0, stream>>>(h_bf, 512, wcat + (size_t)l * 2048 * 512,
                                                      bcat + l * 2048, qkvs, 2048,
                                                      Nn, 2048, 512, 0);
        // fused logits+softmax+aggregate+gelu+residual+LN
        k_attn<<<Nn, 256, 0, stream>>>(qkvs, srcS, offs, h, h_bf,
                                       ln_g + l * 512, ln_b + l * 512);
    }

    // z = gelu(h @ [syn_W|ant_W] + b) -> zB bf16 [Nn][1024]
    gemm_bb<<<dim3(mtiles, 8), 256, 0, stream>>>(h_bf, 512, dualWt, bdual, zB, 1024,
                                                 Nn, 1024, 512, 1);
    // t = z @ W -> tB bf16 [Nn][1024]
    gemm_bb<<<dim3(mtiles, 4), 256, 0, stream>>>(zB, 1024, bilWt, nullptr, tB, 1024,
                                                 Nn, 512, 512, 0);
    gemm_bb<<<dim3(mtiles, 4), 256, 0, stream>>>(zB + 512, 1024, bilWt + 512 * 512, nullptr,
                                                 tB + 512, 1024, Nn, 512, 512, 0);

    k_pairscore<<<(P + 3) / 4, 256, 0, stream>>>(zB, tB, pe, pe + P, ssyn, sant, P);

    k_zero<<<(P + 255) / 256, 256, 0, stream>>>((int*)gpart, P);
    gemm_gate<<<dim3((P + 63) / 64, 2), 256, 0, stream>>>(zB, pe, pe + P, P,
                                                          gw1t, gb1, gW2, gpart);
    k_final<<<(P + 255) / 256, 256, 0, stream>>>(gpart, gb2, ssyn, sant, out, P);
}

// Round 6
// 2088.957 us; speedup vs baseline: 1.4058x; 1.0834x over previous
//
#include <hip/hip_runtime.h>
#include <cstdint>

#define L_LAYERS 6

typedef __attribute__((ext_vector_type(8))) short bf16x8;
typedef __attribute__((ext_vector_type(4))) float f32x4;

__device__ __forceinline__ float gelu1(float v) {
    return 0.5f * v * (1.0f + erff(v * 0.7071067811865475f));
}

__device__ __forceinline__ unsigned int f2bf2(float a, float b) {
    union { float f; unsigned u; } x, y;
    x.f = a; y.f = b;
    unsigned lo = (x.u + 0x7FFFu + ((x.u >> 16) & 1u)) >> 16;
    unsigned hi = (y.u + 0x7FFFu + ((y.u >> 16) & 1u)) & 0xFFFF0000u;
    return lo | hi;
}

__device__ __forceinline__ unsigned short f2bf1(float a) {
    union { float f; unsigned u; } x;
    x.f = a;
    return (unsigned short)((x.u + 0x7FFFu + ((x.u >> 16) & 1u)) >> 16);
}

__device__ __forceinline__ float2 bfp2(unsigned u) {
    union { unsigned u; float f; } a, b;
    a.u = u << 16;
    b.u = u & 0xFFFF0000u;
    return make_float2(a.f, b.f);
}

// async global->LDS, 16 bytes per lane
__device__ __forceinline__ void gload16(const void* g, void* l) {
    __builtin_amdgcn_global_load_lds(
        (const __attribute__((address_space(1))) void*)g,
        (__attribute__((address_space(3))) void*)l, 16, 0, 0);
}

// ---------------- utility ----------------

__global__ void k_zero(int* __restrict__ p, int n) {
    int i = blockIdx.x * 256 + threadIdx.x;
    if (i < n) p[i] = 0;
}

// ---------------- edge sorting (counting sort by dst) ----------------

__global__ void k_hist(const int* __restrict__ dst, int* __restrict__ hist, int E) {
    int e = blockIdx.x * 256 + threadIdx.x;
    if (e < E) atomicAdd(&hist[dst[e]], 1);
}

__global__ __launch_bounds__(1024) void k_scan(const int* __restrict__ hist,
                                               int* __restrict__ off, int n) {
    __shared__ int buf[1024];
    __shared__ int carry;
    int tid = threadIdx.x;
    if (tid == 0) carry = 0;
    __syncthreads();
    for (int base = 0; base < n; base += 1024) {
        int v = (base + tid < n) ? hist[base + tid] : 0;
        buf[tid] = v;
        __syncthreads();
        int x = v;
        for (int o = 1; o < 1024; o <<= 1) {
            int t = (tid >= o) ? buf[tid - o] : 0;
            __syncthreads();
            x += t;
            buf[tid] = x;
            __syncthreads();
        }
        int c = carry;
        if (base + tid < n) off[base + tid] = c + x - v;   // exclusive
        __syncthreads();
        if (tid == 1023) carry = c + buf[1023];
        __syncthreads();
    }
    if (tid == 0) off[n] = carry;
}

__global__ void k_scatter(const int* __restrict__ src, const int* __restrict__ dst,
                          const int* __restrict__ off, int* __restrict__ cursor,
                          int* __restrict__ srcS, int E) {
    int e = blockIdx.x * 256 + threadIdx.x;
    if (e < E) {
        int d = dst[e];
        int pos = off[d] + atomicAdd(&cursor[d], 1);
        srcS[pos] = src[e];
    }
}

// ---------------- weight prep (transpose + cvt to bf16) ----------------

__global__ void k_wcat(const float* __restrict__ Wq, const float* __restrict__ Wk,
                       const float* __restrict__ Wv, const float* __restrict__ Ws,
                       short* __restrict__ Wt) {
    int idx = blockIdx.x * 256 + threadIdx.x;   // l*2^20 + n*512 + k
    int k = idx & 511;
    int nf = (idx >> 9) & 2047;
    int l = idx >> 20;
    int sel = nf >> 9, nn = nf & 511;
    const float* W = (sel == 0) ? Wq : (sel == 1) ? Wk : (sel == 2) ? Wv : Ws;
    float v = W[((size_t)l * 512 + k) * 512 + nn];
    Wt[idx] = (short)f2bf1(v);
}

__global__ void k_tr(const float* __restrict__ W, short* __restrict__ Wt, int K, int N) {
    int k = blockIdx.x * 256 + threadIdx.x;
    int n = blockIdx.y;
    if (k < K) Wt[(size_t)n * K + k] = (short)f2bf1(W[(size_t)k * N + n]);
}

__global__ void k_bcat(const float* __restrict__ bq, const float* __restrict__ bk,
                       const float* __restrict__ bv, const float* __restrict__ bs,
                       float* __restrict__ bcat) {
    int idx = blockIdx.x * 256 + threadIdx.x;
    if (idx >= L_LAYERS * 2048) return;
    int l = idx >> 11, n = idx & 2047;
    int sel = n >> 9, nn = n & 511;
    const float* b = (sel == 0) ? bq : (sel == 1) ? bk : (sel == 2) ? bv : bs;
    bcat[idx] = b[l * 512 + nn];
}

__global__ void k_bdual(const float* __restrict__ sb, const float* __restrict__ ab,
                        float* __restrict__ bd) {
    int idx = blockIdx.x * 256 + threadIdx.x;
    if (idx < 1024) bd[idx] = (idx < 512) ? sb[idx] : ab[idx - 512];
}

// ---------------- GEMM: A fp32 (mixer only) ----------------

__global__ __launch_bounds__(256) void gemm_a32(
    const float* __restrict__ A, int lda,
    const short* __restrict__ Bt,
    const float* __restrict__ bias,
    float* __restrict__ Cf, short* __restrict__ Cbf, int ldc,
    int M, int N, int K, int act) {
    __shared__ __align__(16) short As[128][40];
    __shared__ __align__(16) short Bs[128][40];
    const int tid = threadIdx.x;
    const int lane = tid & 63;
    const int wave = tid >> 6;
    const int wr = (wave >> 1) * 64;
    const int wc = (wave & 1) * 64;
    const int l16 = lane & 15;
    const int quad = lane >> 4;
    const int row0 = blockIdx.x * 128;
    const int col0 = blockIdx.y * 128;
    const int sr = tid >> 2;
    const int sk = (tid & 3) * 8;

    f32x4 acc[4][4];
#pragma unroll
    for (int i = 0; i < 4; ++i)
#pragma unroll
        for (int j = 0; j < 4; ++j)
            acc[i][j] = f32x4{0.f, 0.f, 0.f, 0.f};

    for (int kb = 0; kb < K; kb += 32) {
#pragma unroll
        for (int hh = 0; hh < 2; ++hh) {
            int r = sr + hh * 64;
            int gr = row0 + r;
            float4 a0, a1;
            if (gr < M) {
                const float* p = A + (size_t)gr * lda + kb + sk;
                a0 = *(const float4*)p;
                a1 = *(const float4*)(p + 4);
            } else {
                a0 = make_float4(0.f, 0.f, 0.f, 0.f);
                a1 = make_float4(0.f, 0.f, 0.f, 0.f);
            }
            uint4 av;
            av.x = f2bf2(a0.x, a0.y);
            av.y = f2bf2(a0.z, a0.w);
            av.z = f2bf2(a1.x, a1.y);
            av.w = f2bf2(a1.z, a1.w);
            *(uint4*)&As[r][sk] = av;
            const short* bp = Bt + (size_t)(col0 + r) * K + kb + sk;
            *(uint4*)&Bs[r][sk] = *(const uint4*)bp;
        }
        __syncthreads();
        bf16x8 af[4], bfr[4];
#pragma unroll
        for (int i = 0; i < 4; ++i)
            af[i] = *(const bf16x8*)&As[wr + i * 16 + l16][quad * 8];
#pragma unroll
        for (int j = 0; j < 4; ++j)
            bfr[j] = *(const bf16x8*)&Bs[wc + j * 16 + l16][quad * 8];
#pragma unroll
        for (int i = 0; i < 4; ++i)
#pragma unroll
            for (int j = 0; j < 4; ++j)
                acc[i][j] = __builtin_amdgcn_mfma_f32_16x16x32_bf16(af[i], bfr[j], acc[i][j], 0, 0, 0);
        __syncthreads();
    }
#pragma unroll
    for (int i = 0; i < 4; ++i) {
        int rbase = row0 + wr + i * 16 + quad * 4;
#pragma unroll
        for (int j = 0; j < 4; ++j) {
            int c = col0 + wc + j * 16 + l16;
            float bv = bias ? bias[c] : 0.0f;
#pragma unroll
            for (int rg = 0; rg < 4; ++rg) {
                int gr = rbase + rg;
                if (gr < M) {
                    float v = acc[i][j][rg] + bv;
                    if (act) v = gelu1(v);
                    Cf[(size_t)gr * ldc + c] = v;
                    if (Cbf) Cbf[(size_t)gr * ldc + c] = (short)f2bf1(v);
                }
            }
        }
    }
}

// ---------------- GEMM: A bf16, B bf16, m97-style global_load_lds staging ----------------

__global__ __launch_bounds__(256) void gemm_bb(
    const short* __restrict__ A, int lda,
    const short* __restrict__ Bt,
    const float* __restrict__ bias,
    short* __restrict__ C, int ldc,
    int M, int N, int K, int act) {
    __shared__ __align__(16) short As[128 * 32];
    __shared__ __align__(16) short Bs[128 * 32];
    const int tid = threadIdx.x;
    const int lane = tid & 63;
    const int wave = tid >> 6;
    const int wr = (wave >> 1) * 64;
    const int wc = (wave & 1) * 64;
    const int l16 = lane & 15;
    const int quad = lane >> 4;
    const int row0 = blockIdx.x * 128;
    const int col0 = blockIdx.y * 128;
    const int c0 = tid, c1 = tid + 256;
    const int r0 = c0 >> 2, kq0 = (c0 & 3) * 8;
    const int r1 = c1 >> 2, kq1 = (c1 & 3) * 8;
    int ga0 = row0 + r0; if (ga0 >= M) ga0 = M - 1;
    int ga1 = row0 + r1; if (ga1 >= M) ga1 = M - 1;
    const short* Ap0 = A + (size_t)ga0 * lda + kq0;
    const short* Ap1 = A + (size_t)ga1 * lda + kq1;
    const short* Bp0 = Bt + (size_t)(col0 + r0) * K + kq0;
    const short* Bp1 = Bt + (size_t)(col0 + r1) * K + kq1;

    f32x4 acc[4][4];
#pragma unroll
    for (int i = 0; i < 4; ++i)
#pragma unroll
        for (int j = 0; j < 4; ++j)
            acc[i][j] = f32x4{0.f, 0.f, 0.f, 0.f};

    for (int kb = 0; kb < K; kb += 32) {
        gload16(Ap0 + kb, &As[c0 * 8]);
        gload16(Ap1 + kb, &As[c1 * 8]);
        gload16(Bp0 + kb, &Bs[c0 * 8]);
        gload16(Bp1 + kb, &Bs[c1 * 8]);
        __syncthreads();
        bf16x8 af[4], bfr[4];
#pragma unroll
        for (int i = 0; i < 4; ++i)
            af[i] = *(const bf16x8*)&As[(wr + i * 16 + l16) * 32 + quad * 8];
#pragma unroll
        for (int j = 0; j < 4; ++j)
            bfr[j] = *(const bf16x8*)&Bs[(wc + j * 16 + l16) * 32 + quad * 8];
#pragma unroll
        for (int i = 0; i < 4; ++i)
#pragma unroll
            for (int j = 0; j < 4; ++j)
                acc[i][j] = __builtin_amdgcn_mfma_f32_16x16x32_bf16(af[i], bfr[j], acc[i][j], 0, 0, 0);
        __syncthreads();
    }
#pragma unroll
    for (int i = 0; i < 4; ++i) {
        int rbase = row0 + wr + i * 16 + quad * 4;
#pragma unroll
        for (int j = 0; j < 4; ++j) {
            int c = col0 + wc + j * 16 + l16;
            float bv = bias ? bias[c] : 0.0f;
#pragma unroll
            for (int rg = 0; rg < 4; ++rg) {
                int gr = rbase + rg;
                if (gr < M) {
                    float v = acc[i][j][rg] + bv;
                    if (act) v = gelu1(v);
                    C[(size_t)gr * ldc + c] = (short)f2bf1(v);
                }
            }
        }
    }
}

// ---------------- fused gate GEMM (pairing trick) ----------------

__global__ __launch_bounds__(256, 3) void gemm_gate(
    const short* __restrict__ z,
    const int* __restrict__ pi, const int* __restrict__ pj, int P,
    const short* __restrict__ Bt,    // gW1^T [512][2048]
    const float* __restrict__ gb1,
    const float* __restrict__ gW2,
    float* __restrict__ gpart) {
    __shared__ __align__(16) short Aab[64][40];
    __shared__ __align__(16) short Amu[64][40];
    __shared__ __align__(16) short Bab[256][40];
    __shared__ __align__(16) short Bmu[256][40];
    __shared__ int iArr[64];
    __shared__ int jArr[64];
    __shared__ float rowsum[64];
    const int tid = threadIdx.x;
    const int lane = tid & 63;
    const int wave = tid >> 6;
    const int wc = wave * 64;
    const int l16 = lane & 15;
    const int quad = lane >> 4;
    const int row0 = blockIdx.x * 64;
    const int col0 = blockIdx.y * 256;
    const int sr = tid >> 2;
    const int sk = (tid & 3) * 8;

    if (tid < 64) {
        int p = row0 + tid;
        int ok = (p < P);
        iArr[tid] = ok ? pi[p] : 0;
        jArr[tid] = ok ? pj[p] : 0;
        rowsum[tid] = 0.0f;
    }
    __syncthreads();
    const short* zi = z + (size_t)iArr[sr] * 1024 + sk;
    const short* zj = z + (size_t)jArr[sr] * 1024 + sk;
    const short* bp0 = Bt + (size_t)(col0 + sr) * 2048 + sk;

    f32x4 acc[4][4];
#pragma unroll
    for (int i = 0; i < 4; ++i)
#pragma unroll
        for (int j = 0; j < 4; ++j)
            acc[i][j] = f32x4{0.f, 0.f, 0.f, 0.f};

    for (int part = 0; part < 2; ++part) {
        for (int c = 0; c < 512; c += 32) {
            uint4 xu = *(const uint4*)(zi + part * 512 + c);
            uint4 yu = *(const uint4*)(zj + part * 512 + c);
            float2 x0 = bfp2(xu.x), x1 = bfp2(xu.y), x2 = bfp2(xu.z), x3 = bfp2(xu.w);
            float2 y0 = bfp2(yu.x), y1 = bfp2(yu.y), y2 = bfp2(yu.z), y3 = bfp2(yu.w);
            uint4 aa, am;
            aa.x = f2bf2(fabsf(x0.x - y0.x), fabsf(x0.y - y0.y));
            aa.y = f2bf2(fabsf(x1.x - y1.x), fabsf(x1.y - y1.y));
            aa.z = f2bf2(fabsf(x2.x - y2.x), fabsf(x2.y - y2.y));
            aa.w = f2bf2(fabsf(x3.x - y3.x), fabsf(x3.y - y3.y));
            am.x = f2bf2(x0.x * y0.x, x0.y * y0.y);
            am.y = f2bf2(x1.x * y1.x, x1.y * y1.y);
            am.z = f2bf2(x2.x * y2.x, x2.y * y2.y);
            am.w = f2bf2(x3.x * y3.x, x3.y * y3.y);
            *(uint4*)&Aab[sr][sk] = aa;
            *(uint4*)&Amu[sr][sk] = am;
            const short* bp = bp0 + part * 1024 + c;
#pragma unroll
            for (int hh = 0; hh < 4; ++hh) {
                const short* q = bp + (size_t)hh * 64 * 2048;
                *(uint4*)&Bab[sr + hh * 64][sk] = *(const uint4*)q;
                *(uint4*)&Bmu[sr + hh * 64][sk] = *(const uint4*)(q + 512);
            }
            __syncthreads();
            bf16x8 af[4];
#pragma unroll
            for (int i = 0; i < 4; ++i)
                af[i] = *(const bf16x8*)&Aab[i * 16 + l16][quad * 8];
#pragma unroll
            for (int j = 0; j < 4; ++j) {
                bf16x8 bf = *(const bf16x8*)&Bab[wc + j * 16 + l16][quad * 8];
#pragma unroll
                for (int i = 0; i < 4; ++i)
                    acc[i][j] = __builtin_amdgcn_mfma_f32_16x16x32_bf16(af[i], bf, acc[i][j], 0, 0, 0);
            }
#pragma unroll
            for (int i = 0; i < 4; ++i)
                af[i] = *(const bf16x8*)&Amu[i * 16 + l16][quad * 8];
#pragma unroll
            for (int j = 0; j < 4; ++j) {
                bf16x8 bf = *(const bf16x8*)&Bmu[wc + j * 16 + l16][quad * 8];
#pragma unroll
                for (int i = 0; i < 4; ++i)
                    acc[i][j] = __builtin_amdgcn_mfma_f32_16x16x32_bf16(af[i], bf, acc[i][j], 0, 0, 0);
            }
            __syncthreads();
        }
    }
#pragma unroll
    for (int i = 0; i < 4; ++i) {
#pragma unroll
        for (int rg = 0; rg < 4; ++rg) {
            float partial = 0.f;
#pragma unroll
            for (int j = 0; j < 4; ++j) {
                int cc = col0 + wc + j * 16 + l16;
                partial += gelu1(acc[i][j][rg] + gb1[cc]) * gW2[cc];
            }
            partial += __shfl_xor(partial, 1);
            partial += __shfl_xor(partial, 2);
            partial += __shfl_xor(partial, 4);
            partial += __shfl_xor(partial, 8);
            if (l16 == 0)
                atomicAdd(&rowsum[i * 16 + quad * 4 + rg], partial);
        }
    }
    __syncthreads();
    if (tid < 64 && (row0 + tid) < P)
        atomicAdd(&gpart[row0 + tid], rowsum[tid]);
}

// ---------------- fused per-layer attention: WAVE-PER-NODE, barrier-free ----------------
// qkvs bf16 [Nn][2048]: q|k|v|s at +0/+512/+1024/+1536. 4 waves/block, wave w -> node
// blockIdx.x*4+w. Online softmax per head in registers; logits chunk (<=64 edges) in LDS
// (wave-synchronous, no __syncthreads). Phase 1: 16-lane groups own alternating edges
// (4 edges in flight). Phase 3: whole wave aggregates one edge's v row per uint4 load.

__global__ __launch_bounds__(256) void k_attn(const short* __restrict__ qkvs,
                                              const int* __restrict__ srcS,
                                              const int* __restrict__ offs,
                                              float* __restrict__ h,
                                              short* __restrict__ h_bf,
                                              const float* __restrict__ lng,
                                              const float* __restrict__ lnb, int Nn) {
    __shared__ float Llog[4][64][4];
    const int tid = threadIdx.x;
    const int lane = tid & 63;
    const int wv = tid >> 6;
    const int n = blockIdx.x * 4 + wv;
    if (n >= Nn) return;
    const int g = lane >> 4;     // phase-1 edge group; phases 2/3 head index
    const int li = lane & 15;
    const int st = offs[n], en = offs[n + 1];

    // unpack q rows for all 4 heads (this lane's 8-channel slice of each head)
    float q[4][8];
#pragma unroll
    for (int hh = 0; hh < 4; ++hh) {
        uint4 qv = *(const uint4*)(qkvs + (size_t)n * 2048 + hh * 128 + li * 8);
        float2 t0 = bfp2(qv.x), t1 = bfp2(qv.y), t2 = bfp2(qv.z), t3 = bfp2(qv.w);
        q[hh][0] = t0.x; q[hh][1] = t0.y; q[hh][2] = t1.x; q[hh][3] = t1.y;
        q[hh][4] = t2.x; q[hh][5] = t2.y; q[hh][6] = t3.x; q[hh][7] = t3.y;
    }
    float acc[8];
#pragma unroll
    for (int i = 0; i < 8; ++i) acc[i] = 0.f;
    float m_l = -3.4e38f, l_l = 0.f;

    for (int e0 = st; e0 < en; e0 += 64) {
        int cnt = min(64, en - e0);
        int myS = (lane < cnt) ? srcS[e0 + lane] : 0;
        // --- phase 1: logits; group g handles edges g, g+4, ... (4 in flight) ---
        for (int ei = g; ei < cnt; ei += 4) {
            int s = __shfl(myS, ei);
            const short* kp = qkvs + (size_t)s * 2048 + 512 + li * 8;
            float lg[4];
#pragma unroll
            for (int hh = 0; hh < 4; ++hh) {
                uint4 kv = *(const uint4*)(kp + hh * 128);
                float2 k0 = bfp2(kv.x), k1 = bfp2(kv.y), k2 = bfp2(kv.z), k3 = bfp2(kv.w);
                float d = q[hh][0] * k0.x + q[hh][1] * k0.y + q[hh][2] * k1.x + q[hh][3] * k1.y +
                          q[hh][4] * k2.x + q[hh][5] * k2.y + q[hh][6] * k3.x + q[hh][7] * k3.y;
                d += __shfl_xor(d, 1);
                d += __shfl_xor(d, 2);
                d += __shfl_xor(d, 4);
                d += __shfl_xor(d, 8);
                lg[hh] = d * 0.08838834764831845f;
            }
            if (li == 0)
                *(float4*)&Llog[wv][ei][0] = make_float4(lg[0], lg[1], lg[2], lg[3]);
        }
        // --- phase 2: online softmax, head g handled by its 16-lane group ---
        float mc = -3.4e38f;
        for (int i = li; i < cnt; i += 16) mc = fmaxf(mc, Llog[wv][i][g]);
        mc = fmaxf(mc, __shfl_xor(mc, 1));
        mc = fmaxf(mc, __shfl_xor(mc, 2));
        mc = fmaxf(mc, __shfl_xor(mc, 4));
        mc = fmaxf(mc, __shfl_xor(mc, 8));
        float m_new = fmaxf(m_l, mc);
        float sum = 0.f;
        for (int i = li; i < cnt; i += 16) {
            float p = __expf(Llog[wv][i][g] - m_new);
            Llog[wv][i][g] = p;
            sum += p;
        }
        sum += __shfl_xor(sum, 1);
        sum += __shfl_xor(sum, 2);
        sum += __shfl_xor(sum, 4);
        sum += __shfl_xor(sum, 8);
        float sc = __expf(m_l - m_new);
        l_l = l_l * sc + sum;
        m_l = m_new;
#pragma unroll
        for (int i = 0; i < 8; ++i) acc[i] *= sc;
        // --- phase 3: aggregate; whole wave covers one edge's v row (lane*8 ch) ---
        for (int ei = 0; ei < cnt; ++ei) {
            float a = Llog[wv][ei][g];
            int s = __shfl(myS, ei);
            uint4 vv = *(const uint4*)(qkvs + (size_t)s * 2048 + 1024 + lane * 8);
            float2 v0 = bfp2(vv.x), v1 = bfp2(vv.y), v2 = bfp2(vv.z), v3 = bfp2(vv.w);
            acc[0] += a * v0.x; acc[1] += a * v0.y; acc[2] += a * v1.x; acc[3] += a * v1.y;
            acc[4] += a * v2.x; acc[5] += a * v2.y; acc[6] += a * v3.x; acc[7] += a * v3.y;
        }
    }
    float rinv = (en > st) ? 1.0f / l_l : 0.f;
    // epilogue: + skip, gelu, residual, LN — pure wave shuffles
    uint4 su = *(const uint4*)(qkvs + (size_t)n * 2048 + 1536 + lane * 8);
    float2 s0 = bfp2(su.x), s1 = bfp2(su.y), s2 = bfp2(su.z), s3 = bfp2(su.w);
    float sv[8] = {s0.x, s0.y, s1.x, s1.y, s2.x, s2.y, s3.x, s3.y};
    const float* hp = h + (size_t)n * 512 + lane * 8;
    float4 h0 = *(const float4*)hp;
    float4 h1 = *(const float4*)(hp + 4);
    float hv[8] = {h0.x, h0.y, h0.z, h0.w, h1.x, h1.y, h1.z, h1.w};
    float r[8];
    float sum = 0.f, ssq = 0.f;
#pragma unroll
    for (int i = 0; i < 8; ++i) {
        r[i] = hv[i] + gelu1(acc[i] * rinv + sv[i]);
        sum += r[i];
        ssq += r[i] * r[i];
    }
    for (int o = 32; o; o >>= 1) {
        sum += __shfl_xor(sum, o);
        ssq += __shfl_xor(ssq, o);
    }
    float mean = sum * (1.0f / 512.0f);
    float var = ssq * (1.0f / 512.0f) - mean * mean;
    float inv = rsqrtf(var + 1e-5f);
    const float* gp = lng + lane * 8;
    const float* bp = lnb + lane * 8;
    float4 g0 = *(const float4*)gp, g1 = *(const float4*)(gp + 4);
    float4 b0 = *(const float4*)bp, b1 = *(const float4*)(bp + 4);
    float ga[8] = {g0.x, g0.y, g0.z, g0.w, g1.x, g1.y, g1.z, g1.w};
    float ba[8] = {b0.x, b0.y, b0.z, b0.w, b1.x, b1.y, b1.z, b1.w};
    float o8[8];
#pragma unroll
    for (int i = 0; i < 8; ++i) o8[i] = (r[i] - mean) * inv * ga[i] + ba[i];
    float* hw = h + (size_t)n * 512 + lane * 8;
    *(float4*)hw = make_float4(o8[0], o8[1], o8[2], o8[3]);
    *(float4*)(hw + 4) = make_float4(o8[4], o8[5], o8[6], o8[7]);
    uint4 ob;
    ob.x = f2bf2(o8[0], o8[1]);
    ob.y = f2bf2(o8[2], o8[3]);
    ob.z = f2bf2(o8[4], o8[5]);
    ob.w = f2bf2(o8[6], o8[7]);
    *(uint4*)(h_bf + (size_t)n * 512 + lane * 8) = ob;
}

// ---------------- pair bilinear scores (bf16 z,t) ----------------

__global__ __launch_bounds__(256) void k_pairscore(const short* __restrict__ z,
                                                   const short* __restrict__ t,
                                                   const int* __restrict__ pi,
                                                   const int* __restrict__ pj,
                                                   float* __restrict__ ssyn,
                                                   float* __restrict__ sant, int P) {
    int p = blockIdx.x * 4 + (threadIdx.x >> 6);
    if (p >= P) return;
    int lane = threadIdx.x & 63;
    int i = pi[p], j = pj[p];
    uint4 a = *(const uint4*)(t + (size_t)i * 1024 + lane * 8);
    uint4 b = *(const uint4*)(z + (size_t)j * 1024 + lane * 8);
    float2 a0 = bfp2(a.x), a1 = bfp2(a.y), a2 = bfp2(a.z), a3 = bfp2(a.w);
    float2 b0 = bfp2(b.x), b1 = bfp2(b.y), b2 = bfp2(b.z), b3 = bfp2(b.w);
    float ds = a0.x * b0.x + a0.y * b0.y + a1.x * b1.x + a1.y * b1.y +
               a2.x * b2.x + a2.y * b2.y + a3.x * b3.x + a3.y * b3.y;
    uint4 c = *(const uint4*)(t + (size_t)i * 1024 + 512 + lane * 8);
    uint4 d = *(const uint4*)(z + (size_t)j * 1024 + 512 + lane * 8);
    float2 c0 = bfp2(c.x), c1 = bfp2(c.y), c2 = bfp2(c.z), c3 = bfp2(c.w);
    float2 d0 = bfp2(d.x), d1 = bfp2(d.y), d2 = bfp2(d.z), d3 = bfp2(d.w);
    float da = c0.x * d0.x + c0.y * d0.y + c1.x * d1.x + c1.y * d1.y +
               c2.x * d2.x + c2.y * d2.y + c3.x * d3.x + c3.y * d3.y;
    for (int o = 32; o; o >>= 1) {
        ds += __shfl_xor(ds, o);
        da += __shfl_xor(da, o);
    }
    if (lane == 0) { ssyn[p] = ds; sant[p] = da; }
}

// ---------------- final elementwise combine ----------------

__global__ void k_final(const float* __restrict__ gpart, const float* __restrict__ gb2,
                        const float* __restrict__ ssyn, const float* __restrict__ sant,
                        float* __restrict__ out, int P) {
    int p = blockIdx.x * 256 + threadIdx.x;
    if (p < P) {
        float s = 1.0f / (1.0f + __expf(-(gpart[p] + gb2[0])));
        out[p] = s * sant[p] - (1.0f - s) * ssyn[p];
    }
}

// ---------------- host ----------------

extern "C" void kernel_launch(void* const* d_in, const int* in_sizes, int n_in,
                              void* d_out, int out_size, void* d_ws, size_t ws_size,
                              hipStream_t stream) {
    const float* x = (const float*)d_in[0];
    const int* ei = (const int*)d_in[1];
    const int* pe = (const int*)d_in[2];
    const float* mixer_W = (const float*)d_in[3];
    const float* mixer_b = (const float*)d_in[4];
    const float* Wq = (const float*)d_in[5];
    const float* bq = (const float*)d_in[6];
    const float* Wk = (const float*)d_in[7];
    const float* bk = (const float*)d_in[8];
    const float* Wv = (const float*)d_in[9];
    const float* bv = (const float*)d_in[10];
    const float* Ws = (const float*)d_in[11];
    const float* bs = (const float*)d_in[12];
    const float* ln_g = (const float*)d_in[13];
    const float* ln_b = (const float*)d_in[14];
    const float* syn_W = (const float*)d_in[15];
    const float* syn_b = (const float*)d_in[16];
    const float* ant_W = (const float*)d_in[17];
    const float* ant_b = (const float*)d_in[18];
    const float* W_syn = (const float*)d_in[19];
    const float* W_ant = (const float*)d_in[20];
    const float* gW1 = (const float*)d_in[21];
    const float* gb1 = (const float*)d_in[22];
    const float* gW2 = (const float*)d_in[23];
    const float* gb2 = (const float*)d_in[24];
    float* out = (float*)d_out;

    const int Nn = in_sizes[0] / 768;  // 20000
    const int E = in_sizes[1] / 2;     // 320000
    const int P = in_sizes[2] / 2;     // 100000

    char* w = (char*)d_ws;
    auto alloc = [&](size_t bytes) -> char* {
        char* p = w;
        w += (bytes + 255) & ~(size_t)255;
        return p;
    };
    float* h = (float*)alloc((size_t)Nn * 512 * 4);
    short* h_bf = (short*)alloc((size_t)Nn * 512 * 2);
    short* qkvs = (short*)alloc((size_t)Nn * 2048 * 2);
    short* zB = qkvs;
    short* tB = qkvs + (size_t)Nn * 1024;
    float* ssyn = (float*)alloc((size_t)P * 3 * 4);
    float* sant = ssyn + P;
    float* gpart = ssyn + 2 * P;
    int* srcS = (int*)alloc((size_t)E * 4);
    int* hist = (int*)alloc((size_t)Nn * 2 * 4);
    int* cursor = hist + Nn;
    int* offs = (int*)alloc((size_t)(Nn + 1) * 4);
    short* mixWt = (short*)alloc((size_t)512 * 768 * 2);
    short* wcat = (short*)alloc((size_t)L_LAYERS * 2048 * 512 * 2);
    short* dualWt = (short*)alloc((size_t)1024 * 512 * 2);
    short* bilWt = (short*)alloc((size_t)1024 * 512 * 2);
    short* gw1t = (short*)alloc((size_t)512 * 2048 * 2);
    float* bcat = (float*)alloc((size_t)L_LAYERS * 2048 * 4);
    float* bdual = (float*)alloc((size_t)1024 * 4);

    k_zero<<<(2 * Nn + 255) / 256, 256, 0, stream>>>(hist, 2 * Nn);
    k_hist<<<(E + 255) / 256, 256, 0, stream>>>(ei + E, hist, E);
    k_scan<<<1, 1024, 0, stream>>>(hist, offs, Nn);
    k_scatter<<<(E + 255) / 256, 256, 0, stream>>>(ei, ei + E, offs, cursor, srcS, E);

    k_wcat<<<(L_LAYERS * 2048 * 512) / 256, 256, 0, stream>>>(Wq, Wk, Wv, Ws, wcat);
    k_tr<<<dim3(3, 512), 256, 0, stream>>>(mixer_W, mixWt, 768, 512);
    k_tr<<<dim3(2, 512), 256, 0, stream>>>(syn_W, dualWt, 512, 512);
    k_tr<<<dim3(2, 512), 256, 0, stream>>>(ant_W, dualWt + 512 * 512, 512, 512);
    k_tr<<<dim3(2, 512), 256, 0, stream>>>(W_syn, bilWt, 512, 512);
    k_tr<<<dim3(2, 512), 256, 0, stream>>>(W_ant, bilWt + 512 * 512, 512, 512);
    k_tr<<<dim3(8, 512), 256, 0, stream>>>(gW1, gw1t, 2048, 512);
    k_bcat<<<48, 256, 0, stream>>>(bq, bk, bv, bs, bcat);
    k_bdual<<<4, 256, 0, stream>>>(syn_b, ant_b, bdual);

    const int mtiles = (Nn + 127) / 128;  // 157
    gemm_a32<<<dim3(mtiles, 4), 256, 0, stream>>>(x, 768, mixWt, mixer_b, h, h_bf, 512,
                                                  Nn, 512, 768, 1);

    for (int l = 0; l < L_LAYERS; ++l) {
        gemm_bb<<<dim3(mtiles, 16), 256, 0, stream>>>(h_bf, 512, wcat + (size_t)l * 2048 * 512,
                                                      bcat + l * 2048, qkvs, 2048,
                                                      Nn, 2048, 512, 0);
        k_attn<<<(Nn + 3) / 4, 256, 0, stream>>>(qkvs, srcS, offs, h, h_bf,
                                                 ln_g + l * 512, ln_b + l * 512, Nn);
    }

    gemm_bb<<<dim3(mtiles, 8), 256, 0, stream>>>(h_bf, 512, dualWt, bdual, zB, 1024,
                                                 Nn, 1024, 512, 1);
    gemm_bb<<<dim3(mtiles, 4), 256, 0, stream>>>(zB, 1024, bilWt, nullptr, tB, 1024,
                                                 Nn, 512, 512, 0);
    gemm_bb<<<dim3(mtiles, 4), 256, 0, stream>>>(zB + 512, 1024, bilWt + 512 * 512, nullptr,
                                                 tB + 512, 1024, Nn, 512, 512, 0);

    k_pairscore<<<(P + 3) / 4, 256, 0, stream>>>(zB, tB, pe, pe + P, ssyn, sant, P);

    k_zero<<<(P + 255) / 256, 256, 0, stream>>>((int*)gpart, P);
    gemm_gate<<<dim3((P + 63) / 64, 2), 256, 0, stream>>>(zB, pe, pe + P, P,
                                                          gw1t, gb1, gW2, gpart);
    k_final<<<(P + 255) / 256, 256, 0, stream>>>(gpart, gb2, ssyn, sant, out, P);
}

// Round 7
// 2081.230 us; speedup vs baseline: 1.4111x; 1.0037x over previous
//
#include <hip/hip_runtime.h>
#include <cstdint>

#define L_LAYERS 6

typedef __attribute__((ext_vector_type(8))) short bf16x8;
typedef __attribute__((ext_vector_type(4))) float f32x4;

__device__ __forceinline__ float gelu1(float v) {
    return 0.5f * v * (1.0f + erff(v * 0.7071067811865475f));
}

__device__ __forceinline__ unsigned int f2bf2(float a, float b) {
    union { float f; unsigned u; } x, y;
    x.f = a; y.f = b;
    unsigned lo = (x.u + 0x7FFFu + ((x.u >> 16) & 1u)) >> 16;
    unsigned hi = (y.u + 0x7FFFu + ((y.u >> 16) & 1u)) & 0xFFFF0000u;
    return lo | hi;
}

__device__ __forceinline__ unsigned short f2bf1(float a) {
    union { float f; unsigned u; } x;
    x.f = a;
    return (unsigned short)((x.u + 0x7FFFu + ((x.u >> 16) & 1u)) >> 16);
}

__device__ __forceinline__ float2 bfp2(unsigned u) {
    union { unsigned u; float f; } a, b;
    a.u = u << 16;
    b.u = u & 0xFFFF0000u;
    return make_float2(a.f, b.f);
}

// async global->LDS, 16 bytes per lane (dest = wave-uniform base + lane*16)
__device__ __forceinline__ void gload16(const void* g, void* l) {
    __builtin_amdgcn_global_load_lds(
        (const __attribute__((address_space(1))) void*)g,
        (__attribute__((address_space(3))) void*)l, 16, 0, 0);
}

// ---------------- utility ----------------

__global__ void k_zero(int* __restrict__ p, int n) {
    int i = blockIdx.x * 256 + threadIdx.x;
    if (i < n) p[i] = 0;
}

// ---------------- edge sorting (counting sort by dst) ----------------

__global__ void k_hist(const int* __restrict__ dst, int* __restrict__ hist, int E) {
    int e = blockIdx.x * 256 + threadIdx.x;
    if (e < E) atomicAdd(&hist[dst[e]], 1);
}

__global__ __launch_bounds__(1024) void k_scan(const int* __restrict__ hist,
                                               int* __restrict__ off, int n) {
    __shared__ int buf[1024];
    __shared__ int carry;
    int tid = threadIdx.x;
    if (tid == 0) carry = 0;
    __syncthreads();
    for (int base = 0; base < n; base += 1024) {
        int v = (base + tid < n) ? hist[base + tid] : 0;
        buf[tid] = v;
        __syncthreads();
        int x = v;
        for (int o = 1; o < 1024; o <<= 1) {
            int t = (tid >= o) ? buf[tid - o] : 0;
            __syncthreads();
            x += t;
            buf[tid] = x;
            __syncthreads();
        }
        int c = carry;
        if (base + tid < n) off[base + tid] = c + x - v;   // exclusive
        __syncthreads();
        if (tid == 1023) carry = c + buf[1023];
        __syncthreads();
    }
    if (tid == 0) off[n] = carry;
}

__global__ void k_scatter(const int* __restrict__ src, const int* __restrict__ dst,
                          const int* __restrict__ off, int* __restrict__ cursor,
                          int* __restrict__ srcS, int E) {
    int e = blockIdx.x * 256 + threadIdx.x;
    if (e < E) {
        int d = dst[e];
        int pos = off[d] + atomicAdd(&cursor[d], 1);
        srcS[pos] = src[e];
    }
}

// ---------------- weight prep (transpose + cvt to bf16) ----------------

__global__ void k_wcat(const float* __restrict__ Wq, const float* __restrict__ Wk,
                       const float* __restrict__ Wv, const float* __restrict__ Ws,
                       short* __restrict__ Wt) {
    int idx = blockIdx.x * 256 + threadIdx.x;   // l*2^20 + n*512 + k
    int k = idx & 511;
    int nf = (idx >> 9) & 2047;
    int l = idx >> 20;
    int sel = nf >> 9, nn = nf & 511;
    const float* W = (sel == 0) ? Wq : (sel == 1) ? Wk : (sel == 2) ? Wv : Ws;
    float v = W[((size_t)l * 512 + k) * 512 + nn];
    Wt[idx] = (short)f2bf1(v);
}

__global__ void k_tr(const float* __restrict__ W, short* __restrict__ Wt, int K, int N) {
    int k = blockIdx.x * 256 + threadIdx.x;
    int n = blockIdx.y;
    if (k < K) Wt[(size_t)n * K + k] = (short)f2bf1(W[(size_t)k * N + n]);
}

__global__ void k_bcat(const float* __restrict__ bq, const float* __restrict__ bk,
                       const float* __restrict__ bv, const float* __restrict__ bs,
                       float* __restrict__ bcat) {
    int idx = blockIdx.x * 256 + threadIdx.x;
    if (idx >= L_LAYERS * 2048) return;
    int l = idx >> 11, n = idx & 2047;
    int sel = n >> 9, nn = n & 511;
    const float* b = (sel == 0) ? bq : (sel == 1) ? bk : (sel == 2) ? bv : bs;
    bcat[idx] = b[l * 512 + nn];
}

__global__ void k_bdual(const float* __restrict__ sb, const float* __restrict__ ab,
                        float* __restrict__ bd) {
    int idx = blockIdx.x * 256 + threadIdx.x;
    if (idx < 1024) bd[idx] = (idx < 512) ? sb[idx] : ab[idx - 512];
}

// ---------------- GEMM: A fp32 (mixer only) ----------------

__global__ __launch_bounds__(256) void gemm_a32(
    const float* __restrict__ A, int lda,
    const short* __restrict__ Bt,
    const float* __restrict__ bias,
    float* __restrict__ Cf, short* __restrict__ Cbf, int ldc,
    int M, int N, int K, int act) {
    __shared__ __align__(16) short As[128][40];
    __shared__ __align__(16) short Bs[128][40];
    const int tid = threadIdx.x;
    const int lane = tid & 63;
    const int wave = tid >> 6;
    const int wr = (wave >> 1) * 64;
    const int wc = (wave & 1) * 64;
    const int l16 = lane & 15;
    const int quad = lane >> 4;
    const int row0 = blockIdx.x * 128;
    const int col0 = blockIdx.y * 128;
    const int sr = tid >> 2;
    const int sk = (tid & 3) * 8;

    f32x4 acc[4][4];
#pragma unroll
    for (int i = 0; i < 4; ++i)
#pragma unroll
        for (int j = 0; j < 4; ++j)
            acc[i][j] = f32x4{0.f, 0.f, 0.f, 0.f};

    for (int kb = 0; kb < K; kb += 32) {
#pragma unroll
        for (int hh = 0; hh < 2; ++hh) {
            int r = sr + hh * 64;
            int gr = row0 + r;
            float4 a0, a1;
            if (gr < M) {
                const float* p = A + (size_t)gr * lda + kb + sk;
                a0 = *(const float4*)p;
                a1 = *(const float4*)(p + 4);
            } else {
                a0 = make_float4(0.f, 0.f, 0.f, 0.f);
                a1 = make_float4(0.f, 0.f, 0.f, 0.f);
            }
            uint4 av;
            av.x = f2bf2(a0.x, a0.y);
            av.y = f2bf2(a0.z, a0.w);
            av.z = f2bf2(a1.x, a1.y);
            av.w = f2bf2(a1.z, a1.w);
            *(uint4*)&As[r][sk] = av;
            const short* bp = Bt + (size_t)(col0 + r) * K + kb + sk;
            *(uint4*)&Bs[r][sk] = *(const uint4*)bp;
        }
        __syncthreads();
        bf16x8 af[4], bfr[4];
#pragma unroll
        for (int i = 0; i < 4; ++i)
            af[i] = *(const bf16x8*)&As[wr + i * 16 + l16][quad * 8];
#pragma unroll
        for (int j = 0; j < 4; ++j)
            bfr[j] = *(const bf16x8*)&Bs[wc + j * 16 + l16][quad * 8];
#pragma unroll
        for (int i = 0; i < 4; ++i)
#pragma unroll
            for (int j = 0; j < 4; ++j)
                acc[i][j] = __builtin_amdgcn_mfma_f32_16x16x32_bf16(af[i], bfr[j], acc[i][j], 0, 0, 0);
        __syncthreads();
    }
#pragma unroll
    for (int i = 0; i < 4; ++i) {
        int rbase = row0 + wr + i * 16 + quad * 4;
#pragma unroll
        for (int j = 0; j < 4; ++j) {
            int c = col0 + wc + j * 16 + l16;
            float bv = bias ? bias[c] : 0.0f;
#pragma unroll
            for (int rg = 0; rg < 4; ++rg) {
                int gr = rbase + rg;
                if (gr < M) {
                    float v = acc[i][j][rg] + bv;
                    if (act) v = gelu1(v);
                    Cf[(size_t)gr * ldc + c] = v;
                    if (Cbf) Cbf[(size_t)gr * ldc + c] = (short)f2bf1(v);
                }
            }
        }
    }
}

// ---------------- GEMM: A bf16, B bf16, m97-style global_load_lds staging ----------------

__global__ __launch_bounds__(256) void gemm_bb(
    const short* __restrict__ A, int lda,
    const short* __restrict__ Bt,
    const float* __restrict__ bias,
    short* __restrict__ C, int ldc,
    int M, int N, int K, int act) {
    __shared__ __align__(16) short As[128 * 32];
    __shared__ __align__(16) short Bs[128 * 32];
    const int tid = threadIdx.x;
    const int lane = tid & 63;
    const int wave = tid >> 6;
    const int wr = (wave >> 1) * 64;
    const int wc = (wave & 1) * 64;
    const int l16 = lane & 15;
    const int quad = lane >> 4;
    const int row0 = blockIdx.x * 128;
    const int col0 = blockIdx.y * 128;
    const int c0 = tid, c1 = tid + 256;
    const int r0 = c0 >> 2, kq0 = (c0 & 3) * 8;
    const int r1 = c1 >> 2, kq1 = (c1 & 3) * 8;
    int ga0 = row0 + r0; if (ga0 >= M) ga0 = M - 1;
    int ga1 = row0 + r1; if (ga1 >= M) ga1 = M - 1;
    const short* Ap0 = A + (size_t)ga0 * lda + kq0;
    const short* Ap1 = A + (size_t)ga1 * lda + kq1;
    const short* Bp0 = Bt + (size_t)(col0 + r0) * K + kq0;
    const short* Bp1 = Bt + (size_t)(col0 + r1) * K + kq1;

    f32x4 acc[4][4];
#pragma unroll
    for (int i = 0; i < 4; ++i)
#pragma unroll
        for (int j = 0; j < 4; ++j)
            acc[i][j] = f32x4{0.f, 0.f, 0.f, 0.f};

    for (int kb = 0; kb < K; kb += 32) {
        gload16(Ap0 + kb, &As[c0 * 8]);
        gload16(Ap1 + kb, &As[c1 * 8]);
        gload16(Bp0 + kb, &Bs[c0 * 8]);
        gload16(Bp1 + kb, &Bs[c1 * 8]);
        __syncthreads();
        bf16x8 af[4], bfr[4];
#pragma unroll
        for (int i = 0; i < 4; ++i)
            af[i] = *(const bf16x8*)&As[(wr + i * 16 + l16) * 32 + quad * 8];
#pragma unroll
        for (int j = 0; j < 4; ++j)
            bfr[j] = *(const bf16x8*)&Bs[(wc + j * 16 + l16) * 32 + quad * 8];
#pragma unroll
        for (int i = 0; i < 4; ++i)
#pragma unroll
            for (int j = 0; j < 4; ++j)
                acc[i][j] = __builtin_amdgcn_mfma_f32_16x16x32_bf16(af[i], bfr[j], acc[i][j], 0, 0, 0);
        __syncthreads();
    }
#pragma unroll
    for (int i = 0; i < 4; ++i) {
        int rbase = row0 + wr + i * 16 + quad * 4;
#pragma unroll
        for (int j = 0; j < 4; ++j) {
            int c = col0 + wc + j * 16 + l16;
            float bv = bias ? bias[c] : 0.0f;
#pragma unroll
            for (int rg = 0; rg < 4; ++rg) {
                int gr = rbase + rg;
                if (gr < M) {
                    float v = acc[i][j][rg] + bv;
                    if (act) v = gelu1(v);
                    C[(size_t)gr * ldc + c] = (short)f2bf1(v);
                }
            }
        }
    }
}

// ---------------- fused gate GEMM (pairing trick; conflict-free LDS + async B) ----------
// Unpadded [rows][32] tiles: A write offset = tid*16B (sequential), fragment reads
// identical to gemm_bb's conflict-free pattern. B staged via global_load_lds
// (dest = wave-uniform base + lane*16), overlapping DMA with A-build VALU.

__global__ __launch_bounds__(256, 3) void gemm_gate(
    const short* __restrict__ z,
    const int* __restrict__ pi, const int* __restrict__ pj, int P,
    const short* __restrict__ Bt,    // gW1^T [512][2048]
    const float* __restrict__ gb1,
    const float* __restrict__ gW2,
    float* __restrict__ gpart) {
    __shared__ __align__(16) short Aab[64 * 32];
    __shared__ __align__(16) short Amu[64 * 32];
    __shared__ __align__(16) short Bab[256 * 32];
    __shared__ __align__(16) short Bmu[256 * 32];
    __shared__ int iArr[64];
    __shared__ int jArr[64];
    __shared__ float rowsum[64];
    const int tid = threadIdx.x;
    const int lane = tid & 63;
    const int wave = tid >> 6;
    const int wc = wave * 64;
    const int l16 = lane & 15;
    const int quad = lane >> 4;
    const int row0 = blockIdx.x * 64;
    const int col0 = blockIdx.y * 256;
    const int sr = tid >> 2;        // 0..63
    const int sk = (tid & 3) * 8;

    if (tid < 64) {
        int p = row0 + tid;
        int ok = (p < P);
        iArr[tid] = ok ? pi[p] : 0;
        jArr[tid] = ok ? pj[p] : 0;
        rowsum[tid] = 0.0f;
    }
    __syncthreads();
    const short* zi = z + (size_t)iArr[sr] * 1024 + sk;
    const short* zj = z + (size_t)jArr[sr] * 1024 + sk;
    const short* bp0 = Bt + (size_t)(col0 + sr) * 2048 + sk;

    f32x4 acc[4][4];
#pragma unroll
    for (int i = 0; i < 4; ++i)
#pragma unroll
        for (int j = 0; j < 4; ++j)
            acc[i][j] = f32x4{0.f, 0.f, 0.f, 0.f};

    for (int part = 0; part < 2; ++part) {
        for (int c = 0; c < 512; c += 32) {
            // B async staging first: DMA runs while we build A in VALU
            const short* bp = bp0 + part * 1024 + c;
#pragma unroll
            for (int hh = 0; hh < 4; ++hh) {
                const short* q = bp + (size_t)hh * 64 * 2048;
                gload16(q, &Bab[hh * 2048 + tid * 8]);
                gload16(q + 512, &Bmu[hh * 2048 + tid * 8]);
            }
            // A build: one z gather feeds both abs and mul tiles
            uint4 xu = *(const uint4*)(zi + part * 512 + c);
            uint4 yu = *(const uint4*)(zj + part * 512 + c);
            float2 x0 = bfp2(xu.x), x1 = bfp2(xu.y), x2 = bfp2(xu.z), x3 = bfp2(xu.w);
            float2 y0 = bfp2(yu.x), y1 = bfp2(yu.y), y2 = bfp2(yu.z), y3 = bfp2(yu.w);
            uint4 aa, am;
            aa.x = f2bf2(fabsf(x0.x - y0.x), fabsf(x0.y - y0.y));
            aa.y = f2bf2(fabsf(x1.x - y1.x), fabsf(x1.y - y1.y));
            aa.z = f2bf2(fabsf(x2.x - y2.x), fabsf(x2.y - y2.y));
            aa.w = f2bf2(fabsf(x3.x - y3.x), fabsf(x3.y - y3.y));
            am.x = f2bf2(x0.x * y0.x, x0.y * y0.y);
            am.y = f2bf2(x1.x * y1.x, x1.y * y1.y);
            am.z = f2bf2(x2.x * y2.x, x2.y * y2.y);
            am.w = f2bf2(x3.x * y3.x, x3.y * y3.y);
            *(uint4*)&Aab[tid * 8] = aa;
            *(uint4*)&Amu[tid * 8] = am;
            __syncthreads();
            bf16x8 af[4];
#pragma unroll
            for (int i = 0; i < 4; ++i)
                af[i] = *(const bf16x8*)&Aab[(i * 16 + l16) * 32 + quad * 8];
#pragma unroll
            for (int j = 0; j < 4; ++j) {
                bf16x8 bf = *(const bf16x8*)&Bab[(wc + j * 16 + l16) * 32 + quad * 8];
#pragma unroll
                for (int i = 0; i < 4; ++i)
                    acc[i][j] = __builtin_amdgcn_mfma_f32_16x16x32_bf16(af[i], bf, acc[i][j], 0, 0, 0);
            }
#pragma unroll
            for (int i = 0; i < 4; ++i)
                af[i] = *(const bf16x8*)&Amu[(i * 16 + l16) * 32 + quad * 8];
#pragma unroll
            for (int j = 0; j < 4; ++j) {
                bf16x8 bf = *(const bf16x8*)&Bmu[(wc + j * 16 + l16) * 32 + quad * 8];
#pragma unroll
                for (int i = 0; i < 4; ++i)
                    acc[i][j] = __builtin_amdgcn_mfma_f32_16x16x32_bf16(af[i], bf, acc[i][j], 0, 0, 0);
            }
            __syncthreads();
        }
    }
#pragma unroll
    for (int i = 0; i < 4; ++i) {
#pragma unroll
        for (int rg = 0; rg < 4; ++rg) {
            float partial = 0.f;
#pragma unroll
            for (int j = 0; j < 4; ++j) {
                int cc = col0 + wc + j * 16 + l16;
                partial += gelu1(acc[i][j][rg] + gb1[cc]) * gW2[cc];
            }
            partial += __shfl_xor(partial, 1);
            partial += __shfl_xor(partial, 2);
            partial += __shfl_xor(partial, 4);
            partial += __shfl_xor(partial, 8);
            if (l16 == 0)
                atomicAdd(&rowsum[i * 16 + quad * 4 + rg], partial);
        }
    }
    __syncthreads();
    if (tid < 64 && (row0 + tid) < P)
        atomicAdd(&gpart[row0 + tid], rowsum[tid]);
}

// ---------------- fused per-layer attention: wave-per-node, barrier-free ----------------

__global__ __launch_bounds__(256) void k_attn(const short* __restrict__ qkvs,
                                              const int* __restrict__ srcS,
                                              const int* __restrict__ offs,
                                              float* __restrict__ h,
                                              short* __restrict__ h_bf,
                                              const float* __restrict__ lng,
                                              const float* __restrict__ lnb, int Nn) {
    __shared__ float Llog[4][64][4];
    const int tid = threadIdx.x;
    const int lane = tid & 63;
    const int wv = tid >> 6;
    const int n = blockIdx.x * 4 + wv;
    if (n >= Nn) return;
    const int g = lane >> 4;
    const int li = lane & 15;
    const int st = offs[n], en = offs[n + 1];

    float q[4][8];
#pragma unroll
    for (int hh = 0; hh < 4; ++hh) {
        uint4 qv = *(const uint4*)(qkvs + (size_t)n * 2048 + hh * 128 + li * 8);
        float2 t0 = bfp2(qv.x), t1 = bfp2(qv.y), t2 = bfp2(qv.z), t3 = bfp2(qv.w);
        q[hh][0] = t0.x; q[hh][1] = t0.y; q[hh][2] = t1.x; q[hh][3] = t1.y;
        q[hh][4] = t2.x; q[hh][5] = t2.y; q[hh][6] = t3.x; q[hh][7] = t3.y;
    }
    float acc[8];
#pragma unroll
    for (int i = 0; i < 8; ++i) acc[i] = 0.f;
    float m_l = -3.4e38f, l_l = 0.f;

    for (int e0 = st; e0 < en; e0 += 64) {
        int cnt = min(64, en - e0);
        int myS = (lane < cnt) ? srcS[e0 + lane] : 0;
        for (int ei = g; ei < cnt; ei += 4) {
            int s = __shfl(myS, ei);
            const short* kp = qkvs + (size_t)s * 2048 + 512 + li * 8;
            float lg[4];
#pragma unroll
            for (int hh = 0; hh < 4; ++hh) {
                uint4 kv = *(const uint4*)(kp + hh * 128);
                float2 k0 = bfp2(kv.x), k1 = bfp2(kv.y), k2 = bfp2(kv.z), k3 = bfp2(kv.w);
                float d = q[hh][0] * k0.x + q[hh][1] * k0.y + q[hh][2] * k1.x + q[hh][3] * k1.y +
                          q[hh][4] * k2.x + q[hh][5] * k2.y + q[hh][6] * k3.x + q[hh][7] * k3.y;
                d += __shfl_xor(d, 1);
                d += __shfl_xor(d, 2);
                d += __shfl_xor(d, 4);
                d += __shfl_xor(d, 8);
                lg[hh] = d * 0.08838834764831845f;
            }
            if (li == 0)
                *(float4*)&Llog[wv][ei][0] = make_float4(lg[0], lg[1], lg[2], lg[3]);
        }
        float mc = -3.4e38f;
        for (int i = li; i < cnt; i += 16) mc = fmaxf(mc, Llog[wv][i][g]);
        mc = fmaxf(mc, __shfl_xor(mc, 1));
        mc = fmaxf(mc, __shfl_xor(mc, 2));
        mc = fmaxf(mc, __shfl_xor(mc, 4));
        mc = fmaxf(mc, __shfl_xor(mc, 8));
        float m_new = fmaxf(m_l, mc);
        float sum = 0.f;
        for (int i = li; i < cnt; i += 16) {
            float p = __expf(Llog[wv][i][g] - m_new);
            Llog[wv][i][g] = p;
            sum += p;
        }
        sum += __shfl_xor(sum, 1);
        sum += __shfl_xor(sum, 2);
        sum += __shfl_xor(sum, 4);
        sum += __shfl_xor(sum, 8);
        float sc = __expf(m_l - m_new);
        l_l = l_l * sc + sum;
        m_l = m_new;
#pragma unroll
        for (int i = 0; i < 8; ++i) acc[i] *= sc;
        for (int ei = 0; ei < cnt; ++ei) {
            float a = Llog[wv][ei][g];
            int s = __shfl(myS, ei);
            uint4 vv = *(const uint4*)(qkvs + (size_t)s * 2048 + 1024 + lane * 8);
            float2 v0 = bfp2(vv.x), v1 = bfp2(vv.y), v2 = bfp2(vv.z), v3 = bfp2(vv.w);
            acc[0] += a * v0.x; acc[1] += a * v0.y; acc[2] += a * v1.x; acc[3] += a * v1.y;
            acc[4] += a * v2.x; acc[5] += a * v2.y; acc[6] += a * v3.x; acc[7] += a * v3.y;
        }
    }
    float rinv = (en > st) ? 1.0f / l_l : 0.f;
    uint4 su = *(const uint4*)(qkvs + (size_t)n * 2048 + 1536 + lane * 8);
    float2 s0 = bfp2(su.x), s1 = bfp2(su.y), s2 = bfp2(su.z), s3 = bfp2(su.w);
    float sv[8] = {s0.x, s0.y, s1.x, s1.y, s2.x, s2.y, s3.x, s3.y};
    const float* hp = h + (size_t)n * 512 + lane * 8;
    float4 h0 = *(const float4*)hp;
    float4 h1 = *(const float4*)(hp + 4);
    float hv[8] = {h0.x, h0.y, h0.z, h0.w, h1.x, h1.y, h1.z, h1.w};
    float r[8];
    float sum = 0.f, ssq = 0.f;
#pragma unroll
    for (int i = 0; i < 8; ++i) {
        r[i] = hv[i] + gelu1(acc[i] * rinv + sv[i]);
        sum += r[i];
        ssq += r[i] * r[i];
    }
    for (int o = 32; o; o >>= 1) {
        sum += __shfl_xor(sum, o);
        ssq += __shfl_xor(ssq, o);
    }
    float mean = sum * (1.0f / 512.0f);
    float var = ssq * (1.0f / 512.0f) - mean * mean;
    float inv = rsqrtf(var + 1e-5f);
    const float* gp = lng + lane * 8;
    const float* bp = lnb + lane * 8;
    float4 g0 = *(const float4*)gp, g1 = *(const float4*)(gp + 4);
    float4 b0 = *(const float4*)bp, b1 = *(const float4*)(bp + 4);
    float ga[8] = {g0.x, g0.y, g0.z, g0.w, g1.x, g1.y, g1.z, g1.w};
    float ba[8] = {b0.x, b0.y, b0.z, b0.w, b1.x, b1.y, b1.z, b1.w};
    float o8[8];
#pragma unroll
    for (int i = 0; i < 8; ++i) o8[i] = (r[i] - mean) * inv * ga[i] + ba[i];
    float* hw = h + (size_t)n * 512 + lane * 8;
    *(float4*)hw = make_float4(o8[0], o8[1], o8[2], o8[3]);
    *(float4*)(hw + 4) = make_float4(o8[4], o8[5], o8[6], o8[7]);
    uint4 ob;
    ob.x = f2bf2(o8[0], o8[1]);
    ob.y = f2bf2(o8[2], o8[3]);
    ob.z = f2bf2(o8[4], o8[5]);
    ob.w = f2bf2(o8[6], o8[7]);
    *(uint4*)(h_bf + (size_t)n * 512 + lane * 8) = ob;
}

// ---------------- pair bilinear scores (bf16 z,t) ----------------

__global__ __launch_bounds__(256) void k_pairscore(const short* __restrict__ z,
                                                   const short* __restrict__ t,
                                                   const int* __restrict__ pi,
                                                   const int* __restrict__ pj,
                                                   float* __restrict__ ssyn,
                                                   float* __restrict__ sant, int P) {
    int p = blockIdx.x * 4 + (threadIdx.x >> 6);
    if (p >= P) return;
    int lane = threadIdx.x & 63;
    int i = pi[p], j = pj[p];
    uint4 a = *(const uint4*)(t + (size_t)i * 1024 + lane * 8);
    uint4 b = *(const uint4*)(z + (size_t)j * 1024 + lane * 8);
    float2 a0 = bfp2(a.x), a1 = bfp2(a.y), a2 = bfp2(a.z), a3 = bfp2(a.w);
    float2 b0 = bfp2(b.x), b1 = bfp2(b.y), b2 = bfp2(b.z), b3 = bfp2(b.w);
    float ds = a0.x * b0.x + a0.y * b0.y + a1.x * b1.x + a1.y * b1.y +
               a2.x * b2.x + a2.y * b2.y + a3.x * b3.x + a3.y * b3.y;
    uint4 c = *(const uint4*)(t + (size_t)i * 1024 + 512 + lane * 8);
    uint4 d = *(const uint4*)(z + (size_t)j * 1024 + 512 + lane * 8);
    float2 c0 = bfp2(c.x), c1 = bfp2(c.y), c2 = bfp2(c.z), c3 = bfp2(c.w);
    float2 d0 = bfp2(d.x), d1 = bfp2(d.y), d2 = bfp2(d.z), d3 = bfp2(d.w);
    float da = c0.x * d0.x + c0.y * d0.y + c1.x * d1.x + c1.y * d1.y +
               c2.x * d2.x + c2.y * d2.y + c3.x * d3.x + c3.y * d3.y;
    for (int o = 32; o; o >>= 1) {
        ds += __shfl_xor(ds, o);
        da += __shfl_xor(da, o);
    }
    if (lane == 0) { ssyn[p] = ds; sant[p] = da; }
}

// ---------------- final elementwise combine ----------------

__global__ void k_final(const float* __restrict__ gpart, const float* __restrict__ gb2,
                        const float* __restrict__ ssyn, const float* __restrict__ sant,
                        float* __restrict__ out, int P) {
    int p = blockIdx.x * 256 + threadIdx.x;
    if (p < P) {
        float s = 1.0f / (1.0f + __expf(-(gpart[p] + gb2[0])));
        out[p] = s * sant[p] - (1.0f - s) * ssyn[p];
    }
}

// ---------------- host ----------------

extern "C" void kernel_launch(void* const* d_in, const int* in_sizes, int n_in,
                              void* d_out, int out_size, void* d_ws, size_t ws_size,
                              hipStream_t stream) {
    const float* x = (const float*)d_in[0];
    const int* ei = (const int*)d_in[1];
    const int* pe = (const int*)d_in[2];
    const float* mixer_W = (const float*)d_in[3];
    const float* mixer_b = (const float*)d_in[4];
    const float* Wq = (const float*)d_in[5];
    const float* bq = (const float*)d_in[6];
    const float* Wk = (const float*)d_in[7];
    const float* bk = (const float*)d_in[8];
    const float* Wv = (const float*)d_in[9];
    const float* bv = (const float*)d_in[10];
    const float* Ws = (const float*)d_in[11];
    const float* bs = (const float*)d_in[12];
    const float* ln_g = (const float*)d_in[13];
    const float* ln_b = (const float*)d_in[14];
    const float* syn_W = (const float*)d_in[15];
    const float* syn_b = (const float*)d_in[16];
    const float* ant_W = (const float*)d_in[17];
    const float* ant_b = (const float*)d_in[18];
    const float* W_syn = (const float*)d_in[19];
    const float* W_ant = (const float*)d_in[20];
    const float* gW1 = (const float*)d_in[21];
    const float* gb1 = (const float*)d_in[22];
    const float* gW2 = (const float*)d_in[23];
    const float* gb2 = (const float*)d_in[24];
    float* out = (float*)d_out;

    const int Nn = in_sizes[0] / 768;  // 20000
    const int E = in_sizes[1] / 2;     // 320000
    const int P = in_sizes[2] / 2;     // 100000

    char* w = (char*)d_ws;
    auto alloc = [&](size_t bytes) -> char* {
        char* p = w;
        w += (bytes + 255) & ~(size_t)255;
        return p;
    };
    float* h = (float*)alloc((size_t)Nn * 512 * 4);
    short* h_bf = (short*)alloc((size_t)Nn * 512 * 2);
    short* qkvs = (short*)alloc((size_t)Nn * 2048 * 2);
    short* zB = qkvs;
    short* tB = qkvs + (size_t)Nn * 1024;
    float* ssyn = (float*)alloc((size_t)P * 3 * 4);
    float* sant = ssyn + P;
    float* gpart = ssyn + 2 * P;
    int* srcS = (int*)alloc((size_t)E * 4);
    int* hist = (int*)alloc((size_t)Nn * 2 * 4);
    int* cursor = hist + Nn;
    int* offs = (int*)alloc((size_t)(Nn + 1) * 4);
    short* mixWt = (short*)alloc((size_t)512 * 768 * 2);
    short* wcat = (short*)alloc((size_t)L_LAYERS * 2048 * 512 * 2);
    short* dualWt = (short*)alloc((size_t)1024 * 512 * 2);
    short* bilWt = (short*)alloc((size_t)1024 * 512 * 2);
    short* gw1t = (short*)alloc((size_t)512 * 2048 * 2);
    float* bcat = (float*)alloc((size_t)L_LAYERS * 2048 * 4);
    float* bdual = (float*)alloc((size_t)1024 * 4);

    k_zero<<<(2 * Nn + 255) / 256, 256, 0, stream>>>(hist, 2 * Nn);
    k_hist<<<(E + 255) / 256, 256, 0, stream>>>(ei + E, hist, E);
    k_scan<<<1, 1024, 0, stream>>>(hist, offs, Nn);
    k_scatter<<<(E + 255) / 256, 256, 0, stream>>>(ei, ei + E, offs, cursor, srcS, E);

    k_wcat<<<(L_LAYERS * 2048 * 512) / 256, 256, 0, stream>>>(Wq, Wk, Wv, Ws, wcat);
    k_tr<<<dim3(3, 512), 256, 0, stream>>>(mixer_W, mixWt, 768, 512);
    k_tr<<<dim3(2, 512), 256, 0, stream>>>(syn_W, dualWt, 512, 512);
    k_tr<<<dim3(2, 512), 256, 0, stream>>>(ant_W, dualWt + 512 * 512, 512, 512);
    k_tr<<<dim3(2, 512), 256, 0, stream>>>(W_syn, bilWt, 512, 512);
    k_tr<<<dim3(2, 512), 256, 0, stream>>>(W_ant, bilWt + 512 * 512, 512, 512);
    k_tr<<<dim3(8, 512), 256, 0, stream>>>(gW1, gw1t, 2048, 512);
    k_bcat<<<48, 256, 0, stream>>>(bq, bk, bv, bs, bcat);
    k_bdual<<<4, 256, 0, stream>>>(syn_b, ant_b, bdual);

    const int mtiles = (Nn + 127) / 128;  // 157
    gemm_a32<<<dim3(mtiles, 4), 256, 0, stream>>>(x, 768, mixWt, mixer_b, h, h_bf, 512,
                                                  Nn, 512, 768, 1);

    for (int l = 0; l < L_LAYERS; ++l) {
        gemm_bb<<<dim3(mtiles, 16), 256, 0, stream>>>(h_bf, 512, wcat + (size_t)l * 2048 * 512,
                                                      bcat + l * 2048, qkvs, 2048,
                                                      Nn, 2048, 512, 0);
        k_attn<<<(Nn + 3) / 4, 256, 0, stream>>>(qkvs, srcS, offs, h, h_bf,
                                                 ln_g + l * 512, ln_b + l * 512, Nn);
    }

    gemm_bb<<<dim3(mtiles, 8), 256, 0, stream>>>(h_bf, 512, dualWt, bdual, zB, 1024,
                                                 Nn, 1024, 512, 1);
    gemm_bb<<<dim3(mtiles, 4), 256, 0, stream>>>(zB, 1024, bilWt, nullptr, tB, 1024,
                                                 Nn, 512, 512, 0);
    gemm_bb<<<dim3(mtiles, 4), 256, 0, stream>>>(zB + 512, 1024, bilWt + 512 * 512, nullptr,
                                                 tB + 512, 1024, Nn, 512, 512, 0);

    k_pairscore<<<(P + 3) / 4, 256, 0, stream>>>(zB, tB, pe, pe + P, ssyn, sant, P);

    k_zero<<<(P + 255) / 256, 256, 0, stream>>>((int*)gpart, P);
    gemm_gate<<<dim3((P + 63) / 64, 2), 256, 0, stream>>>(zB, pe, pe + P, P,
                                                          gw1t, gb1, gW2, gpart);
    k_final<<<(P + 255) / 256, 256, 0, stream>>>(gpart, gb2, ssyn, sant, out, P);
}